// Round 1
// baseline (16295.627 us; speedup 1.0000x reference)
//
#include <hip/hip_runtime.h>
#include <cmath>

#define DEV_INLINE __device__ __forceinline__

constexpr int Bn = 128;   // batch
constexpr int Nn = 128;   // points per batch
constexpr int Fn = 13;    // input features
constexpr int Dn = 256;   // model dim
constexpr int Hn = 8;     // heads
constexpr int Ln = 8;     // layers
constexpr int Kn = 10;    // knn
constexpr int FFn = 512;  // hidden
constexpr int HEADn = 32; // head dim
constexpr int Tn = Bn * Nn; // 16384 tokens

// ---------------- static device workspace (fully rewritten every call) ----------------
__device__ float g_big[Tn * 768];  // qkv buffer / 512-wide hidden buffer / shifted-feature buffer
__device__ float g_x[Tn * Dn];
__device__ float g_skip[Tn * Dn];
__device__ float g_lf1[Tn * Dn];   // knn1 out; later attn-proj out
__device__ float g_lf2[Tn * Dn];   // knn2 out; later ffn out
__device__ float g_attn[Tn * Dn];  // distance matrix (B*128*128 fits), later attention out
__device__ float g_u[Bn * FFn];    // time-mlp @ time_w  (scale|shift per batch)
__device__ float g_r[Tn];          // row norms for knn2
__device__ int   g_idx[Tn * Kn];

DEV_INLINE float gelu_f(float x) {
    // jax.nn.gelu approximate=True (tanh form)
    float u = 0.7978845608028654f * (x + 0.044715f * x * x * x);
    return 0.5f * x * (1.f + tanhf(u));
}

// ---------------- time / fourier MLP: u[b] = silu(silu(e@w1)@w2) @ time_w ----------------
__global__ __launch_bounds__(256) void k_time(const float* __restrict__ tin,
                                              const float* __restrict__ w1,
                                              const float* __restrict__ w2,
                                              const float* __restrict__ tw,
                                              float* __restrict__ u) {
    __shared__ float e[256], e1[512], t2[256];
    int b = blockIdx.x, tid = threadIdx.x;
    float tv = tin[b];
    if (tid < 128) {
        const float emb = 0.07252236513366287f; // log(10000)/127
        float fr = expf(-emb * (float)tid);
        float ang = tv * fr * 1000.f;
        e[tid] = sinf(ang);
        e[tid + 128] = cosf(ang);
    }
    __syncthreads();
    for (int j = tid; j < 512; j += 256) {
        float s = 0.f;
        for (int i = 0; i < 256; i++) s += e[i] * w1[(size_t)i * 512 + j];
        e1[j] = s / (1.f + expf(-s));
    }
    __syncthreads();
    {
        float s = 0.f;
        for (int i = 0; i < 512; i++) s += e1[i] * w2[(size_t)i * 256 + tid];
        t2[tid] = s / (1.f + expf(-s));
    }
    __syncthreads();
    for (int j = tid; j < 512; j += 256) {
        float s = 0.f;
        for (int i = 0; i < 256; i++) s += t2[i] * tw[(size_t)i * 512 + j];
        u[(size_t)b * 512 + j] = s;
    }
}

// ---------------- encoder stage 1: H = gelu(feat @ enc_w1 + b1), K=13 ----------------
__global__ __launch_bounds__(256) void k_enc1(const float* __restrict__ feat,
                                              const float* __restrict__ w1,
                                              const float* __restrict__ b1,
                                              float* __restrict__ Hb) {
    __shared__ float f[16];
    int t = blockIdx.x, tid = threadIdx.x;
    if (tid < Fn) f[tid] = feat[(size_t)t * Fn + tid];
    __syncthreads();
    for (int j = tid; j < FFn; j += 256) {
        float s = b1[j];
#pragma unroll
        for (int i = 0; i < Fn; i++) s += f[i] * w1[(size_t)i * FFn + j];
        Hb[(size_t)t * FFn + j] = gelu_f(s);
    }
}

// ---------------- generic f32 GEMM: C = epi(A @ B + bias). 64x64 tile, BK=16 ----------------
template <int EPI> // 0 = none, 1 = gelu
__global__ __launch_bounds__(256) void k_gemm(const float* __restrict__ A,
                                              const float* __restrict__ Bw,
                                              const float* __restrict__ bias,
                                              float* __restrict__ C,
                                              int M, int Kd, int Nd) {
    __shared__ float As[16][68];
    __shared__ float Bs[16][68];
    int tid = threadIdx.x;
    int n0 = blockIdx.x * 64, m0 = blockIdx.y * 64;
    int tx = tid & 15, ty = tid >> 4;
    int ar = tid >> 2, ac = (tid & 3) << 2;
    int br = tid >> 4, bc = (tid & 15) << 2;
    float acc[4][4] = {};
    for (int k0 = 0; k0 < Kd; k0 += 16) {
        float4 av = *(const float4*)&A[(size_t)(m0 + ar) * Kd + k0 + ac];
        float4 bv = *(const float4*)&Bw[(size_t)(k0 + br) * Nd + n0 + bc];
        __syncthreads();
        As[ac + 0][ar] = av.x; As[ac + 1][ar] = av.y;
        As[ac + 2][ar] = av.z; As[ac + 3][ar] = av.w;
        *(float4*)&Bs[br][bc] = bv;
        __syncthreads();
#pragma unroll
        for (int kk = 0; kk < 16; kk++) {
            float4 a = *(const float4*)&As[kk][ty << 2];
            float4 b = *(const float4*)&Bs[kk][tx << 2];
            acc[0][0] += a.x * b.x; acc[0][1] += a.x * b.y; acc[0][2] += a.x * b.z; acc[0][3] += a.x * b.w;
            acc[1][0] += a.y * b.x; acc[1][1] += a.y * b.y; acc[1][2] += a.y * b.z; acc[1][3] += a.y * b.w;
            acc[2][0] += a.z * b.x; acc[2][1] += a.z * b.y; acc[2][2] += a.z * b.z; acc[2][3] += a.z * b.w;
            acc[3][0] += a.w * b.x; acc[3][1] += a.w * b.y; acc[3][2] += a.w * b.z; acc[3][3] += a.w * b.w;
        }
    }
    float4 bv4 = *(const float4*)&bias[n0 + (tx << 2)];
#pragma unroll
    for (int i = 0; i < 4; i++) {
        float4 v;
        v.x = acc[i][0] + bv4.x; v.y = acc[i][1] + bv4.y;
        v.z = acc[i][2] + bv4.z; v.w = acc[i][3] + bv4.w;
        if (EPI == 1) { v.x = gelu_f(v.x); v.y = gelu_f(v.y); v.z = gelu_f(v.z); v.w = gelu_f(v.w); }
        *(float4*)&C[(size_t)(m0 + (ty << 2) + i) * Nd + n0 + (tx << 2)] = v;
    }
}

// ---------------- knn top-k on 2-d points (matches lax.top_k tie rules) ----------------
__global__ __launch_bounds__(128) void k_topk2(const float* __restrict__ pts,
                                               const float* __restrict__ mask,
                                               int* __restrict__ idx) {
    int b = blockIdx.x, n = threadIdx.x;
    __shared__ float px[Nn], py[Nn], rr[Nn];
    float shift = 999.f * (1.f - mask[b * Nn + n]);
    float x = pts[(size_t)(b * Nn + n) * 2 + 0] + shift;
    float y = pts[(size_t)(b * Nn + n) * 2 + 1] + shift;
    px[n] = x; py[n] = y; rr[n] = x * x + y * y;
    __syncthreads();
    float rn = rr[n];
    float bd[Kn + 1]; int bi[Kn + 1];
#pragma unroll
    for (int j = 0; j <= Kn; j++) { bd[j] = 3.4e38f; bi[j] = -1; }
    for (int m = 0; m < Nn; m++) {
        float d = rn - 2.f * (x * px[m] + y * py[m]) + rr[m];
        if (d < bd[Kn]) {
            int j = Kn;
            while (j > 0 && d < bd[j - 1]) { bd[j] = bd[j - 1]; bi[j] = bi[j - 1]; j--; }
            bd[j] = d; bi[j] = m;
        }
    }
    for (int j = 1; j <= Kn; j++) idx[(size_t)(b * Nn + n) * Kn + j - 1] = bi[j];
}

// ---------------- shifted features, row norms, pairwise distances (knn2) ----------------
__global__ void k_shift(const float* __restrict__ lf, const float* __restrict__ mask,
                        float* __restrict__ o) {
    int gid = blockIdx.x * 256 + threadIdx.x;
    int t = gid >> 8;
    o[gid] = lf[gid] + 999.f * (1.f - mask[t]);
}

__global__ __launch_bounds__(64) void k_rnorm(const float* __restrict__ fe, float* __restrict__ r) {
    int t = blockIdx.x, lane = threadIdx.x;
    const float* p = fe + (size_t)t * Dn;
    float s = 0.f;
    for (int i = lane; i < Dn; i += 64) { float v = p[i]; s += v * v; }
#pragma unroll
    for (int off = 32; off; off >>= 1) s += __shfl_xor(s, off, 64);
    if (lane == 0) r[t] = s;
}

__global__ __launch_bounds__(256) void k_dist(const float* __restrict__ fe,
                                              const float* __restrict__ r,
                                              float* __restrict__ Dm) {
    int b = blockIdx.z;
    int m0 = blockIdx.x * 64, n0 = blockIdx.y * 64;
    const float* A = fe + (size_t)b * Nn * Dn;
    __shared__ float As[16][68];
    __shared__ float Bs[16][68];
    int tid = threadIdx.x;
    int tx = tid & 15, ty = tid >> 4;
    int ar = tid >> 2, ac = (tid & 3) << 2;
    float acc[4][4] = {};
    for (int k0 = 0; k0 < Dn; k0 += 16) {
        float4 av = *(const float4*)&A[(size_t)(n0 + ar) * Dn + k0 + ac];
        float4 bv = *(const float4*)&A[(size_t)(m0 + ar) * Dn + k0 + ac];
        __syncthreads();
        As[ac + 0][ar] = av.x; As[ac + 1][ar] = av.y; As[ac + 2][ar] = av.z; As[ac + 3][ar] = av.w;
        Bs[ac + 0][ar] = bv.x; Bs[ac + 1][ar] = bv.y; Bs[ac + 2][ar] = bv.z; Bs[ac + 3][ar] = bv.w;
        __syncthreads();
#pragma unroll
        for (int kk = 0; kk < 16; kk++) {
            float4 a = *(const float4*)&As[kk][ty << 2];
            float4 b2 = *(const float4*)&Bs[kk][tx << 2];
            acc[0][0] += a.x * b2.x; acc[0][1] += a.x * b2.y; acc[0][2] += a.x * b2.z; acc[0][3] += a.x * b2.w;
            acc[1][0] += a.y * b2.x; acc[1][1] += a.y * b2.y; acc[1][2] += a.y * b2.z; acc[1][3] += a.y * b2.w;
            acc[2][0] += a.z * b2.x; acc[2][1] += a.z * b2.y; acc[2][2] += a.z * b2.z; acc[2][3] += a.z * b2.w;
            acc[3][0] += a.w * b2.x; acc[3][1] += a.w * b2.y; acc[3][2] += a.w * b2.z; acc[3][3] += a.w * b2.w;
        }
    }
    float4 rm = *(const float4*)&r[b * Nn + m0 + (tx << 2)];
#pragma unroll
    for (int i = 0; i < 4; i++) {
        int n = n0 + (ty << 2) + i;
        float rn = r[b * Nn + n];
        float4 v;
        v.x = rn - 2.f * acc[i][0] + rm.x;
        v.y = rn - 2.f * acc[i][1] + rm.y;
        v.z = rn - 2.f * acc[i][2] + rm.z;
        v.w = rn - 2.f * acc[i][3] + rm.w;
        *(float4*)&Dm[(size_t)b * Nn * Nn + (size_t)n * Nn + m0 + (tx << 2)] = v;
    }
}

__global__ __launch_bounds__(128) void k_topkg(const float* __restrict__ Dm, int* __restrict__ idx) {
    int b = blockIdx.x, n = threadIdx.x;
    const float* row = Dm + (size_t)b * Nn * Nn + (size_t)n * Nn;
    float bd[Kn + 1]; int bi[Kn + 1];
#pragma unroll
    for (int j = 0; j <= Kn; j++) { bd[j] = 3.4e38f; bi[j] = -1; }
    for (int m = 0; m < Nn; m++) {
        float d = row[m];
        if (d < bd[Kn]) {
            int j = Kn;
            while (j > 0 && d < bd[j - 1]) { bd[j] = bd[j - 1]; bi[j] = bi[j - 1]; j--; }
            bd[j] = d; bi[j] = m;
        }
    }
    for (int j = 1; j <= Kn; j++) idx[(size_t)(b * Nn + n) * Kn + j - 1] = bi[j];
}

// ---------------- fused per-token KNN MLP: mean_k gelu(gelu(local@w1+b1)@w2+b2) ----------------
template <int IN>
__global__ __launch_bounds__(256) void k_knn_mlp(const float* __restrict__ feats,
                                                 const int* __restrict__ idx,
                                                 const float* __restrict__ w1,
                                                 const float* __restrict__ b1,
                                                 const float* __restrict__ w2,
                                                 const float* __restrict__ b2,
                                                 float* __restrict__ outp) {
    constexpr int LOC = 2 * IN;
    __shared__ float loc[Kn][LOC];
    __shared__ float h1[Kn][FFn];
    __shared__ float red[4][Dn];
    int t = blockIdx.x, tid = threadIdx.x;
    int b = t >> 7;
    const float* cf = feats + (size_t)t * IN;
    for (int k = 0; k < Kn; k++) {
        int nb = idx[(size_t)t * Kn + k];
        const float* nf = feats + (size_t)(b * Nn + nb) * IN;
        for (int c = tid; c < IN; c += 256) {
            float ce = cf[c];
            loc[k][c] = nf[c] - ce;
            loc[k][IN + c] = ce;
        }
    }
    __syncthreads();
    // h1 phase: waves split k into halves of 5; each thread owns 4 output cols
    {
        int j = (tid & 127) << 2;
        int kh = tid >> 7; // 0 or 1
        float acc[5][4];
        float4 bv = *(const float4*)&b1[j];
#pragma unroll
        for (int kk = 0; kk < 5; kk++) { acc[kk][0] = bv.x; acc[kk][1] = bv.y; acc[kk][2] = bv.z; acc[kk][3] = bv.w; }
        for (int i = 0; i < LOC; i++) {
            float4 w = *(const float4*)&w1[(size_t)i * FFn + j];
#pragma unroll
            for (int kk = 0; kk < 5; kk++) {
                float lv = loc[kh * 5 + kk][i];
                acc[kk][0] += lv * w.x; acc[kk][1] += lv * w.y; acc[kk][2] += lv * w.z; acc[kk][3] += lv * w.w;
            }
        }
#pragma unroll
        for (int kk = 0; kk < 5; kk++) {
            float4 hv;
            hv.x = gelu_f(acc[kk][0]); hv.y = gelu_f(acc[kk][1]);
            hv.z = gelu_f(acc[kk][2]); hv.w = gelu_f(acc[kk][3]);
            *(float4*)&h1[kh * 5 + kk][j] = hv;
        }
    }
    __syncthreads();
    // h2 phase: waves split k by residue mod 4 (subsets {0,4,8},{1,5,9},{2,6},{3,7})
    {
        int c = (tid & 63) << 2;
        int kq = tid >> 6;
        int nk = (Kn - kq + 3) >> 2;
        float acc[3][4];
        float4 bv = *(const float4*)&b2[c];
        for (int kk = 0; kk < nk; kk++) { acc[kk][0] = bv.x; acc[kk][1] = bv.y; acc[kk][2] = bv.z; acc[kk][3] = bv.w; }
        for (int i = 0; i < FFn; i++) {
            float4 w = *(const float4*)&w2[(size_t)i * Dn + c];
            for (int kk = 0; kk < nk; kk++) {
                float hv = h1[kq + kk * 4][i];
                acc[kk][0] += hv * w.x; acc[kk][1] += hv * w.y; acc[kk][2] += hv * w.z; acc[kk][3] += hv * w.w;
            }
        }
        float4 p; p.x = p.y = p.z = p.w = 0.f;
        for (int kk = 0; kk < nk; kk++) {
            p.x += gelu_f(acc[kk][0]); p.y += gelu_f(acc[kk][1]);
            p.z += gelu_f(acc[kk][2]); p.w += gelu_f(acc[kk][3]);
        }
        *(float4*)&red[kq][c] = p;
    }
    __syncthreads();
    {
        int c = tid;
        float s = red[0][c] + red[1][c] + red[2][c] + red[3][c];
        outp[(size_t)t * Dn + c] = s * 0.1f;
    }
}

// ---------------- combine: x = enc*(1+mask*u_scale) + mask*u_shift + lf2 ; skip = x ----------------
__global__ void k_combine(const float* __restrict__ u, const float* __restrict__ mask,
                          const float* __restrict__ lf2, float* __restrict__ x,
                          float* __restrict__ skip) {
    int gid = blockIdx.x * 256 + threadIdx.x;
    int t = gid >> 6;
    int c = (gid & 63) << 2;
    int b = t >> 7;
    float m = mask[t];
    float4 xv = *(const float4*)&x[(size_t)t * Dn + c];
    float4 lv = *(const float4*)&lf2[(size_t)t * Dn + c];
    float4 sc = *(const float4*)&u[(size_t)b * 512 + c];
    float4 sh = *(const float4*)&u[(size_t)b * 512 + 256 + c];
    float4 v;
    v.x = xv.x * (1.f + m * sc.x) + m * sh.x + lv.x;
    v.y = xv.y * (1.f + m * sc.y) + m * sh.y + lv.y;
    v.z = xv.z * (1.f + m * sc.z) + m * sh.z + lv.z;
    v.w = xv.w * (1.f + m * sc.w) + m * sh.w + lv.w;
    *(float4*)&x[(size_t)t * Dn + c] = v;
    *(float4*)&skip[(size_t)t * Dn + c] = v;
}

// ---------------- attention: one block per (b,h), thread = query row, 2-pass softmax ----------------
__global__ __launch_bounds__(128) void k_attn(const float* __restrict__ qkv,
                                              const float* __restrict__ mask,
                                              float* __restrict__ outp) {
    int bh = blockIdx.x;
    int b = bh >> 3, h = bh & 7;
    __shared__ float Ks[Nn][36], Vs[Nn][36], msk[Nn];
    int tid = threadIdx.x;
    const float* rowp = qkv + (size_t)(b * Nn + tid) * 768;
#pragma unroll
    for (int c = 0; c < HEADn; c += 4) {
        *(float4*)&Ks[tid][c] = *(const float4*)&rowp[256 + h * 32 + c];
        *(float4*)&Vs[tid][c] = *(const float4*)&rowp[512 + h * 32 + c];
    }
    msk[tid] = mask[b * Nn + tid];
    float q[32];
#pragma unroll
    for (int c = 0; c < 32; c++) q[c] = rowp[h * 32 + c];
    __syncthreads();
    const float sc = 0.17677669529663687f; // 1/sqrt(32)
    float mx = -3.0e38f;
    for (int m = 0; m < Nn; m++) {
        float s = 0.f;
#pragma unroll
        for (int c = 0; c < 32; c += 4) {
            float4 kv = *(const float4*)&Ks[m][c];
            s += q[c] * kv.x + q[c + 1] * kv.y + q[c + 2] * kv.z + q[c + 3] * kv.w;
        }
        s *= sc;
        s = msk[m] > 0.f ? s : -1.0e9f;
        mx = fmaxf(mx, s);
    }
    float l = 0.f;
    float o[32];
#pragma unroll
    for (int c = 0; c < 32; c++) o[c] = 0.f;
    for (int m = 0; m < Nn; m++) {
        float s = 0.f;
#pragma unroll
        for (int c = 0; c < 32; c += 4) {
            float4 kv = *(const float4*)&Ks[m][c];
            s += q[c] * kv.x + q[c + 1] * kv.y + q[c + 2] * kv.z + q[c + 3] * kv.w;
        }
        s *= sc;
        s = msk[m] > 0.f ? s : -1.0e9f;
        float p = __expf(s - mx);
        l += p;
#pragma unroll
        for (int c = 0; c < 32; c += 4) {
            float4 vv = *(const float4*)&Vs[m][c];
            o[c] += p * vv.x; o[c + 1] += p * vv.y; o[c + 2] += p * vv.z; o[c + 3] += p * vv.w;
        }
    }
    float inv = 1.f / l;
    float* op = outp + (size_t)(b * Nn + tid) * Dn + h * 32;
#pragma unroll
    for (int c = 0; c < 32; c += 4) {
        float4 v; v.x = o[c] * inv; v.y = o[c + 1] * inv; v.z = o[c + 2] * inv; v.w = o[c + 3] * inv;
        *(float4*)&op[c] = v;
    }
}

// ---------------- layernorm: out = LN(res + delta[*gamma*mask]) * g + beta ----------------
template <bool PM>
__global__ __launch_bounds__(256) void k_ln(const float* __restrict__ res,
                                            const float* __restrict__ del,
                                            const float* __restrict__ g,
                                            const float* __restrict__ beta,
                                            const float* __restrict__ gamma,
                                            const float* __restrict__ mask,
                                            float* __restrict__ outp) {
    int wid = threadIdx.x >> 6, lane = threadIdx.x & 63;
    int t = blockIdx.x * 4 + wid;
    int c = lane << 2;
    float4 rv = *(const float4*)&res[(size_t)t * Dn + c];
    float4 dv = *(const float4*)&del[(size_t)t * Dn + c];
    float x0, x1, x2, x3;
    if (PM) {
        float m = mask[t];
        x0 = rv.x + dv.x * gamma[c + 0] * m;
        x1 = rv.y + dv.y * gamma[c + 1] * m;
        x2 = rv.z + dv.z * gamma[c + 2] * m;
        x3 = rv.w + dv.w * gamma[c + 3] * m;
    } else {
        x0 = rv.x + dv.x; x1 = rv.y + dv.y; x2 = rv.z + dv.z; x3 = rv.w + dv.w;
    }
    float s = x0 + x1 + x2 + x3;
#pragma unroll
    for (int off = 1; off < 64; off <<= 1) s += __shfl_xor(s, off, 64);
    float mean = s * (1.f / 256.f);
    float e0 = x0 - mean, e1 = x1 - mean, e2 = x2 - mean, e3 = x3 - mean;
    float qd = e0 * e0 + e1 * e1 + e2 * e2 + e3 * e3;
#pragma unroll
    for (int off = 1; off < 64; off <<= 1) qd += __shfl_xor(qd, off, 64);
    float rs = rsqrtf(qd * (1.f / 256.f) + 1e-5f);
    float4 ov;
    ov.x = e0 * rs * g[c + 0] + beta[c + 0];
    ov.y = e1 * rs * g[c + 1] + beta[c + 1];
    ov.z = e2 * rs * g[c + 2] + beta[c + 2];
    ov.w = e3 * rs * g[c + 3] + beta[c + 3];
    *(float4*)&outp[(size_t)t * Dn + c] = ov;
}

__global__ void k_out(const float* __restrict__ x, const float* __restrict__ skip,
                      float* __restrict__ o) {
    int gid = blockIdx.x * 256 + threadIdx.x;
    float4 a = *(const float4*)&x[(size_t)gid * 4];
    float4 b = *(const float4*)&skip[(size_t)gid * 4];
    float4 v; v.x = a.x + b.x; v.y = a.y + b.y; v.z = a.z + b.z; v.w = a.w + b.w;
    *(float4*)&o[(size_t)gid * 4] = v;
}

extern "C" void kernel_launch(void* const* d_in, const int* in_sizes, int n_in,
                              void* d_out, int out_size, void* d_ws, size_t ws_size,
                              hipStream_t stream) {
    (void)in_sizes; (void)n_in; (void)out_size; (void)d_ws; (void)ws_size;
    const float* f_feat = (const float*)d_in[0];
    const float* f_pts  = (const float*)d_in[1];
    const float* f_mask = (const float*)d_in[2];
    const float* f_time = (const float*)d_in[3];
    const float* enc_w1 = (const float*)d_in[4];
    const float* enc_b1 = (const float*)d_in[5];
    const float* enc_w2 = (const float*)d_in[6];
    const float* enc_b2 = (const float*)d_in[7];
    const float* four_w1 = (const float*)d_in[8];
    const float* four_w2 = (const float*)d_in[9];
    const float* time_w = (const float*)d_in[10];
    const float* l1w1 = (const float*)d_in[11];
    const float* l1b1 = (const float*)d_in[12];
    const float* l1w2 = (const float*)d_in[13];
    const float* l1b2 = (const float*)d_in[14];
    const float* l2w1 = (const float*)d_in[15];
    const float* l2b1 = (const float*)d_in[16];
    const float* l2w2 = (const float*)d_in[17];
    const float* l2b2 = (const float*)d_in[18];
    const float* qkv_w = (const float*)d_in[19];
    const float* qkv_b = (const float*)d_in[20];
    const float* out_w = (const float*)d_in[21];
    const float* out_b = (const float*)d_in[22];
    const float* ln1g = (const float*)d_in[23];
    const float* ln1b = (const float*)d_in[24];
    const float* ff1w = (const float*)d_in[25];
    const float* ff1b = (const float*)d_in[26];
    const float* ff2w = (const float*)d_in[27];
    const float* ff2b = (const float*)d_in[28];
    const float* gam  = (const float*)d_in[29];
    const float* ln2g = (const float*)d_in[30];
    const float* ln2b = (const float*)d_in[31];
    float* out = (float*)d_out;

    float *big, *x, *skip, *lf1, *lf2, *attn, *u, *r;
    int* idx;
    hipGetSymbolAddress((void**)&big,  HIP_SYMBOL(g_big));
    hipGetSymbolAddress((void**)&x,    HIP_SYMBOL(g_x));
    hipGetSymbolAddress((void**)&skip, HIP_SYMBOL(g_skip));
    hipGetSymbolAddress((void**)&lf1,  HIP_SYMBOL(g_lf1));
    hipGetSymbolAddress((void**)&lf2,  HIP_SYMBOL(g_lf2));
    hipGetSymbolAddress((void**)&attn, HIP_SYMBOL(g_attn));
    hipGetSymbolAddress((void**)&u,    HIP_SYMBOL(g_u));
    hipGetSymbolAddress((void**)&r,    HIP_SYMBOL(g_r));
    hipGetSymbolAddress((void**)&idx,  HIP_SYMBOL(g_idx));

    // time embedding -> u
    k_time<<<Bn, 256, 0, stream>>>(f_time, four_w1, four_w2, time_w, u);
    // encoder
    k_enc1<<<Tn, 256, 0, stream>>>(f_feat, enc_w1, enc_b1, big);
    k_gemm<1><<<dim3(Dn / 64, Tn / 64), 256, 0, stream>>>(big, enc_w2, enc_b2, x, Tn, 512, 256);
    // knn pass 1 (2-d points, raw features)
    k_topk2<<<Bn, Nn, 0, stream>>>(f_pts, f_mask, idx);
    k_knn_mlp<13><<<Tn, 256, 0, stream>>>(f_feat, idx, l1w1, l1b1, l1w2, l1b2, lf1);
    // knn pass 2 (256-d feature-space distances)
    k_shift<<<Tn * Dn / 256, 256, 0, stream>>>(lf1, f_mask, big);
    k_rnorm<<<Tn, 64, 0, stream>>>(big, r);
    k_dist<<<dim3(2, 2, Bn), 256, 0, stream>>>(big, r, attn);
    k_topkg<<<Bn, Nn, 0, stream>>>(attn, idx);
    k_knn_mlp<256><<<Tn, 256, 0, stream>>>(lf1, idx, l2w1, l2b1, l2w2, l2b2, lf2);
    // combine (time modulation + local features); set skip
    k_combine<<<Tn * 64 / 256, 256, 0, stream>>>(u, f_mask, lf2, x, skip);
    // transformer layers
    for (int l = 0; l < Ln; l++) {
        k_gemm<0><<<dim3(768 / 64, Tn / 64), 256, 0, stream>>>(
            x, qkv_w + (size_t)l * Dn * 768, qkv_b + (size_t)l * 768, big, Tn, 256, 768);
        k_attn<<<Bn * Hn, 128, 0, stream>>>(big, f_mask, attn);
        k_gemm<0><<<dim3(Dn / 64, Tn / 64), 256, 0, stream>>>(
            attn, out_w + (size_t)l * Dn * Dn, out_b + (size_t)l * Dn, lf1, Tn, 256, 256);
        k_ln<false><<<Tn / 4, 256, 0, stream>>>(x, lf1, ln1g + l * Dn, ln1b + l * Dn, nullptr, f_mask, x);
        k_gemm<1><<<dim3(FFn / 64, Tn / 64), 256, 0, stream>>>(
            x, ff1w + (size_t)l * Dn * FFn, ff1b + (size_t)l * FFn, big, Tn, 256, 512);
        k_gemm<0><<<dim3(Dn / 64, Tn / 64), 256, 0, stream>>>(
            big, ff2w + (size_t)l * FFn * Dn, ff2b + (size_t)l * Dn, lf2, Tn, 512, 256);
        k_ln<true><<<Tn / 4, 256, 0, stream>>>(x, lf2, ln2g + l * Dn, ln2b + l * Dn, gam + l * Dn, f_mask, x);
    }
    // final residual
    k_out<<<Tn * 64 / 256, 256, 0, stream>>>(x, skip, out);
}

// Round 2
// 2942.411 us; speedup vs baseline: 5.5382x; 5.5382x over previous
//
#include <hip/hip_runtime.h>
#include <cmath>

#define DEV_INLINE __device__ __forceinline__

constexpr int Bn = 128;   // batch
constexpr int Nn = 128;   // points per batch
constexpr int Fn = 13;    // input features
constexpr int Dn = 256;   // model dim
constexpr int Hn = 8;     // heads
constexpr int Ln = 8;     // layers
constexpr int Kn = 10;    // knn
constexpr int FFn = 512;  // hidden
constexpr int HEADn = 32; // head dim
constexpr int Tn = Bn * Nn; // 16384 tokens
constexpr int Rn = Tn * Kn; // 163840 gathered rows

typedef __attribute__((ext_vector_type(4))) float f32x4;
typedef __attribute__((ext_vector_type(8))) short bf16x8;

// ---------------- static device workspace (every read region fully rewritten per call) ----------------
__device__ float g_big[Tn * 768];
__device__ float g_x[Tn * Dn];
__device__ float g_skip[Tn * Dn];
__device__ float g_lf1[Tn * Dn];
__device__ float g_lf2[Tn * Dn];
__device__ float g_attn[Tn * Dn];   // distance matrix / attention out
__device__ float g_u[Bn * FFn];
__device__ float g_r[Tn];
__device__ int   g_idx[Tn * Kn];
__device__ unsigned short g_loc[Rn * 512];  // gathered local rows, bf16
__device__ unsigned short g_h1[Rn * 512];   // knn hidden, bf16
__device__ float          g_h2[Rn * 256];   // knn out pre-mean, f32
// transposed bf16 weights [N][Kpad]
constexpr int OFF_ENC2 = 0;
constexpr int OFF_L1W1 = OFF_ENC2 + 256 * 512;
constexpr int OFF_L1W2 = OFF_L1W1 + 512 * 32;
constexpr int OFF_L2W1 = OFF_L1W2 + 256 * 512;
constexpr int OFF_L2W2 = OFF_L2W1 + 512 * 512;
constexpr int OFF_QKV  = OFF_L2W2 + 256 * 512;
constexpr int OFF_OUT  = OFF_QKV + 8 * 768 * 256;
constexpr int OFF_FF1  = OFF_OUT + 8 * 256 * 256;
constexpr int OFF_FF2  = OFF_FF1 + 8 * 512 * 256;
constexpr int WT_TOTAL = OFF_FF2 + 8 * 256 * 512;
__device__ unsigned short g_wt[WT_TOTAL];

DEV_INLINE float gelu_f(float x) {
    float u = 0.7978845608028654f * (x + 0.044715f * x * x * x);
    return 0.5f * x * (1.f + tanhf(u));
}

DEV_INLINE unsigned short f2b(float x) {
    unsigned int u = __float_as_uint(x);
    u += 0x7FFFu + ((u >> 16) & 1u);
    return (unsigned short)(u >> 16);
}

// ---------------- weight prep: f32 [K][N] -> bf16 [N][Kpad] (transpose + cvt + zero-pad K) ----------------
__global__ __launch_bounds__(256) void k_prep(const float* __restrict__ src,
                                              unsigned short* __restrict__ dst,
                                              int Kreal, int Kpad, int Nd,
                                              long sstride, long dstride) {
    __shared__ float tile[32][33];
    int l = blockIdx.z;
    const float* s = src + (size_t)l * sstride;
    unsigned short* d = dst + (size_t)l * dstride;
    int tid = threadIdx.x;
    int cn = tid & 31, rk = tid >> 5;
    int kbase = blockIdx.y * 32, nbase = blockIdx.x * 32;
#pragma unroll
    for (int p = 0; p < 4; p++) {
        int k = kbase + p * 8 + rk;
        float v = (k < Kreal) ? s[(size_t)k * Nd + nbase + cn] : 0.f;
        tile[p * 8 + rk][cn] = v;
    }
    __syncthreads();
#pragma unroll
    for (int p = 0; p < 4; p++) {
        int nl = p * 8 + rk;
        d[(size_t)(nbase + nl) * Kpad + kbase + cn] = f2b(tile[cn][nl]);
    }
}

// ---------------- MFMA GEMM: C[M][Nd] = epi(A[M][Kd] @ Bt^T + bias), Bt = bf16 [Nd][Kd] ----------------
// 128x128 tile, BK=32, 256 threads (4 waves, each 64x64). A f32 (cvt in staging) or bf16.
template <bool ABF, int EPI, bool OBF>
__global__ __launch_bounds__(256) void k_mgemm(const void* __restrict__ Ap,
                                               const unsigned short* __restrict__ Bt,
                                               const float* __restrict__ bias,
                                               void* __restrict__ Cp,
                                               int Kd, int Nd) {
    __shared__ unsigned short As[128 * 40];
    __shared__ unsigned short Bs[128 * 40];
    int tid = threadIdx.x;
    int m0 = blockIdx.y << 7, n0 = blockIdx.x << 7;
    int lane = tid & 63, wave = tid >> 6;
    int wm = (wave & 1) << 6, wn = (wave >> 1) << 6;
    int lm = lane & 15, quad = lane >> 4;
    f32x4 acc[4][4] = {};
    int srow = tid >> 1, scol = (tid & 1) << 4; // each thread stages 16 elems of one row
    const float* af32 = (const float*)Ap + (size_t)(m0 + srow) * Kd + scol;
    const unsigned short* abf = (const unsigned short*)Ap + (size_t)(m0 + srow) * Kd + scol;
    const unsigned short* bp = Bt + (size_t)(n0 + srow) * Kd + scol;
    int sdst = srow * 40 + scol; // ushort units

    for (int k0 = 0; k0 < Kd; k0 += 32) {
        uint4 pb0 = *(const uint4*)bp;
        uint4 pb1 = *(const uint4*)(bp + 8);
        uint4 pa0, pa1;
        if constexpr (ABF) {
            pa0 = *(const uint4*)abf;
            pa1 = *(const uint4*)(abf + 8);
            abf += 32;
        } else {
            float4 a0 = *(const float4*)(af32);
            float4 a1 = *(const float4*)(af32 + 4);
            float4 a2 = *(const float4*)(af32 + 8);
            float4 a3 = *(const float4*)(af32 + 12);
            af32 += 32;
            pa0.x = (unsigned)f2b(a0.x) | ((unsigned)f2b(a0.y) << 16);
            pa0.y = (unsigned)f2b(a0.z) | ((unsigned)f2b(a0.w) << 16);
            pa0.z = (unsigned)f2b(a1.x) | ((unsigned)f2b(a1.y) << 16);
            pa0.w = (unsigned)f2b(a1.z) | ((unsigned)f2b(a1.w) << 16);
            pa1.x = (unsigned)f2b(a2.x) | ((unsigned)f2b(a2.y) << 16);
            pa1.y = (unsigned)f2b(a2.z) | ((unsigned)f2b(a2.w) << 16);
            pa1.z = (unsigned)f2b(a3.x) | ((unsigned)f2b(a3.y) << 16);
            pa1.w = (unsigned)f2b(a3.z) | ((unsigned)f2b(a3.w) << 16);
        }
        bp += 32;
        __syncthreads();
        *(uint4*)&As[sdst] = pa0;
        *(uint4*)&As[sdst + 8] = pa1;
        *(uint4*)&Bs[sdst] = pb0;
        *(uint4*)&Bs[sdst + 8] = pb1;
        __syncthreads();
        bf16x8 afr[4], bfr[4];
#pragma unroll
        for (int i = 0; i < 4; i++) {
            afr[i] = *(const bf16x8*)&As[(wm + i * 16 + lm) * 40 + (quad << 3)];
            bfr[i] = *(const bf16x8*)&Bs[(wn + i * 16 + lm) * 40 + (quad << 3)];
        }
#pragma unroll
        for (int mf = 0; mf < 4; mf++)
#pragma unroll
            for (int nf = 0; nf < 4; nf++)
                acc[mf][nf] = __builtin_amdgcn_mfma_f32_16x16x32_bf16(afr[mf], bfr[nf], acc[mf][nf], 0, 0, 0);
    }
    float bvs[4];
#pragma unroll
    for (int nf = 0; nf < 4; nf++) bvs[nf] = bias[n0 + wn + nf * 16 + lm];
#pragma unroll
    for (int mf = 0; mf < 4; mf++) {
#pragma unroll
        for (int r = 0; r < 4; r++) {
            size_t row = (size_t)(m0 + wm + mf * 16 + (quad << 2) + r);
#pragma unroll
            for (int nf = 0; nf < 4; nf++) {
                float v = acc[mf][nf][r] + bvs[nf];
                if (EPI == 1) v = gelu_f(v);
                size_t ci = row * Nd + n0 + wn + nf * 16 + lm;
                if constexpr (OBF) ((unsigned short*)Cp)[ci] = f2b(v);
                else ((float*)Cp)[ci] = v;
            }
        }
    }
}

// ---------------- time / fourier MLP ----------------
__global__ __launch_bounds__(256) void k_time(const float* __restrict__ tin,
                                              const float* __restrict__ w1,
                                              const float* __restrict__ w2,
                                              const float* __restrict__ tw,
                                              float* __restrict__ u) {
    __shared__ float e[256], e1[512], t2[256];
    int b = blockIdx.x, tid = threadIdx.x;
    float tv = tin[b];
    if (tid < 128) {
        const float emb = 0.07252236513366287f;
        float fr = expf(-emb * (float)tid);
        float ang = tv * fr * 1000.f;
        e[tid] = sinf(ang);
        e[tid + 128] = cosf(ang);
    }
    __syncthreads();
    for (int j = tid; j < 512; j += 256) {
        float s = 0.f;
        for (int i = 0; i < 256; i++) s += e[i] * w1[(size_t)i * 512 + j];
        e1[j] = s / (1.f + expf(-s));
    }
    __syncthreads();
    {
        float s = 0.f;
        for (int i = 0; i < 512; i++) s += e1[i] * w2[(size_t)i * 256 + tid];
        t2[tid] = s / (1.f + expf(-s));
    }
    __syncthreads();
    for (int j = tid; j < 512; j += 256) {
        float s = 0.f;
        for (int i = 0; i < 256; i++) s += t2[i] * tw[(size_t)i * 512 + j];
        u[(size_t)b * 512 + j] = s;
    }
}

// ---------------- encoder stage 1 (K=13) ----------------
__global__ __launch_bounds__(256) void k_enc1(const float* __restrict__ feat,
                                              const float* __restrict__ w1,
                                              const float* __restrict__ b1,
                                              float* __restrict__ Hb) {
    __shared__ float f[16];
    int t = blockIdx.x, tid = threadIdx.x;
    if (tid < Fn) f[tid] = feat[(size_t)t * Fn + tid];
    __syncthreads();
    for (int j = tid; j < FFn; j += 256) {
        float s = b1[j];
#pragma unroll
        for (int i = 0; i < Fn; i++) s += f[i] * w1[(size_t)i * FFn + j];
        Hb[(size_t)t * FFn + j] = gelu_f(s);
    }
}

// ---------------- knn top-k on 2-d points ----------------
__global__ __launch_bounds__(128) void k_topk2(const float* __restrict__ pts,
                                               const float* __restrict__ mask,
                                               int* __restrict__ idx) {
    int b = blockIdx.x, n = threadIdx.x;
    __shared__ float px[Nn], py[Nn], rr[Nn];
    float shift = 999.f * (1.f - mask[b * Nn + n]);
    float x = pts[(size_t)(b * Nn + n) * 2 + 0] + shift;
    float y = pts[(size_t)(b * Nn + n) * 2 + 1] + shift;
    px[n] = x; py[n] = y; rr[n] = x * x + y * y;
    __syncthreads();
    float rn = rr[n];
    float bd[Kn + 1]; int bi[Kn + 1];
#pragma unroll
    for (int j = 0; j <= Kn; j++) { bd[j] = 3.4e38f; bi[j] = -1; }
    for (int m = 0; m < Nn; m++) {
        float d = rn - 2.f * (x * px[m] + y * py[m]) + rr[m];
        if (d < bd[Kn]) {
            int j = Kn;
            while (j > 0 && d < bd[j - 1]) { bd[j] = bd[j - 1]; bi[j] = bi[j - 1]; j--; }
            bd[j] = d; bi[j] = m;
        }
    }
    for (int j = 1; j <= Kn; j++) idx[(size_t)(b * Nn + n) * Kn + j - 1] = bi[j];
}

__global__ void k_shift(const float* __restrict__ lf, const float* __restrict__ mask,
                        float* __restrict__ o) {
    int gid = blockIdx.x * 256 + threadIdx.x;
    int t = gid >> 8;
    o[gid] = lf[gid] + 999.f * (1.f - mask[t]);
}

__global__ __launch_bounds__(64) void k_rnorm(const float* __restrict__ fe, float* __restrict__ r) {
    int t = blockIdx.x, lane = threadIdx.x;
    const float* p = fe + (size_t)t * Dn;
    float s = 0.f;
    for (int i = lane; i < Dn; i += 64) { float v = p[i]; s += v * v; }
#pragma unroll
    for (int off = 32; off; off >>= 1) s += __shfl_xor(s, off, 64);
    if (lane == 0) r[t] = s;
}

__global__ __launch_bounds__(256) void k_dist(const float* __restrict__ fe,
                                              const float* __restrict__ r,
                                              float* __restrict__ Dm) {
    int b = blockIdx.z;
    int m0 = blockIdx.x * 64, n0 = blockIdx.y * 64;
    const float* A = fe + (size_t)b * Nn * Dn;
    __shared__ float As[16][68];
    __shared__ float Bs[16][68];
    int tid = threadIdx.x;
    int tx = tid & 15, ty = tid >> 4;
    int ar = tid >> 2, ac = (tid & 3) << 2;
    float acc[4][4] = {};
    for (int k0 = 0; k0 < Dn; k0 += 16) {
        float4 av = *(const float4*)&A[(size_t)(n0 + ar) * Dn + k0 + ac];
        float4 bv = *(const float4*)&A[(size_t)(m0 + ar) * Dn + k0 + ac];
        __syncthreads();
        As[ac + 0][ar] = av.x; As[ac + 1][ar] = av.y; As[ac + 2][ar] = av.z; As[ac + 3][ar] = av.w;
        Bs[ac + 0][ar] = bv.x; Bs[ac + 1][ar] = bv.y; Bs[ac + 2][ar] = bv.z; Bs[ac + 3][ar] = bv.w;
        __syncthreads();
#pragma unroll
        for (int kk = 0; kk < 16; kk++) {
            float4 a = *(const float4*)&As[kk][ty << 2];
            float4 b2 = *(const float4*)&Bs[kk][tx << 2];
            acc[0][0] += a.x * b2.x; acc[0][1] += a.x * b2.y; acc[0][2] += a.x * b2.z; acc[0][3] += a.x * b2.w;
            acc[1][0] += a.y * b2.x; acc[1][1] += a.y * b2.y; acc[1][2] += a.y * b2.z; acc[1][3] += a.y * b2.w;
            acc[2][0] += a.z * b2.x; acc[2][1] += a.z * b2.y; acc[2][2] += a.z * b2.z; acc[2][3] += a.z * b2.w;
            acc[3][0] += a.w * b2.x; acc[3][1] += a.w * b2.y; acc[3][2] += a.w * b2.z; acc[3][3] += a.w * b2.w;
        }
    }
    float4 rm = *(const float4*)&r[b * Nn + m0 + (tx << 2)];
#pragma unroll
    for (int i = 0; i < 4; i++) {
        int n = n0 + (ty << 2) + i;
        float rn = r[b * Nn + n];
        float4 v;
        v.x = rn - 2.f * acc[i][0] + rm.x;
        v.y = rn - 2.f * acc[i][1] + rm.y;
        v.z = rn - 2.f * acc[i][2] + rm.z;
        v.w = rn - 2.f * acc[i][3] + rm.w;
        *(float4*)&Dm[(size_t)b * Nn * Nn + (size_t)n * Nn + m0 + (tx << 2)] = v;
    }
}

__global__ __launch_bounds__(128) void k_topkg(const float* __restrict__ Dm, int* __restrict__ idx) {
    int b = blockIdx.x, n = threadIdx.x;
    const float* row = Dm + (size_t)b * Nn * Nn + (size_t)n * Nn;
    float bd[Kn + 1]; int bi[Kn + 1];
#pragma unroll
    for (int j = 0; j <= Kn; j++) { bd[j] = 3.4e38f; bi[j] = -1; }
    for (int m = 0; m < Nn; m++) {
        float d = row[m];
        if (d < bd[Kn]) {
            int j = Kn;
            while (j > 0 && d < bd[j - 1]) { bd[j] = bd[j - 1]; bi[j] = bi[j - 1]; j--; }
            bd[j] = d; bi[j] = m;
        }
    }
    for (int j = 1; j <= Kn; j++) idx[(size_t)(b * Nn + n) * Kn + j - 1] = bi[j];
}

// ---------------- gathers: build local rows (bf16) ----------------
__global__ __launch_bounds__(256) void k_gather1(const float* __restrict__ feats,
                                                 const int* __restrict__ idx,
                                                 unsigned short* __restrict__ loc) {
    int t = blockIdx.x; int b = t >> 7;
    int tid = threadIdx.x;
    __shared__ float cf[16];
    if (tid < Fn) cf[tid] = feats[(size_t)t * Fn + tid];
    __syncthreads();
    for (int e = tid; e < Kn * 32; e += 256) {
        int k = e >> 5, c = e & 31;
        float v;
        if (c < Fn) {
            int nb = idx[t * Kn + k];
            v = feats[(size_t)(b * Nn + nb) * Fn + c] - cf[c];
        } else if (c < 2 * Fn) {
            v = cf[c - Fn];
        } else v = 0.f;
        loc[(size_t)(t * Kn + k) * 32 + c] = f2b(v);
    }
}

__global__ __launch_bounds__(256) void k_gather2(const float* __restrict__ lf,
                                                 const int* __restrict__ idx,
                                                 unsigned short* __restrict__ loc) {
    int row = blockIdx.x; // t*Kn + k
    int t = row / Kn;
    int b = t >> 7;
    int nb = idx[row];
    int c = threadIdx.x;
    float ce = lf[(size_t)t * Dn + c];
    float nf = lf[(size_t)(b * Nn + nb) * Dn + c];
    unsigned short* o = loc + (size_t)row * 512;
    o[c] = f2b(nf - ce);
    o[256 + c] = f2b(ce);
}

__global__ __launch_bounds__(256) void k_mean(const float* __restrict__ h2, float* __restrict__ o) {
    int t = blockIdx.x, c = threadIdx.x;
    const float* p = h2 + (size_t)t * Kn * 256 + c;
    float s = 0.f;
#pragma unroll
    for (int k = 0; k < Kn; k++) s += p[k * 256];
    o[(size_t)t * 256 + c] = s * 0.1f;
}

// ---------------- combine ----------------
__global__ void k_combine(const float* __restrict__ u, const float* __restrict__ mask,
                          const float* __restrict__ lf2, float* __restrict__ x,
                          float* __restrict__ skip) {
    int gid = blockIdx.x * 256 + threadIdx.x;
    int t = gid >> 6;
    int c = (gid & 63) << 2;
    int b = t >> 7;
    float m = mask[t];
    float4 xv = *(const float4*)&x[(size_t)t * Dn + c];
    float4 lv = *(const float4*)&lf2[(size_t)t * Dn + c];
    float4 sc = *(const float4*)&u[(size_t)b * 512 + c];
    float4 sh = *(const float4*)&u[(size_t)b * 512 + 256 + c];
    float4 v;
    v.x = xv.x * (1.f + m * sc.x) + m * sh.x + lv.x;
    v.y = xv.y * (1.f + m * sc.y) + m * sh.y + lv.y;
    v.z = xv.z * (1.f + m * sc.z) + m * sh.z + lv.z;
    v.w = xv.w * (1.f + m * sc.w) + m * sh.w + lv.w;
    *(float4*)&x[(size_t)t * Dn + c] = v;
    *(float4*)&skip[(size_t)t * Dn + c] = v;
}

// ---------------- attention ----------------
__global__ __launch_bounds__(128) void k_attn(const float* __restrict__ qkv,
                                              const float* __restrict__ mask,
                                              float* __restrict__ outp) {
    int bh = blockIdx.x;
    int b = bh >> 3, h = bh & 7;
    __shared__ float Ks[Nn][36], Vs[Nn][36], msk[Nn];
    int tid = threadIdx.x;
    const float* rowp = qkv + (size_t)(b * Nn + tid) * 768;
#pragma unroll
    for (int c = 0; c < HEADn; c += 4) {
        *(float4*)&Ks[tid][c] = *(const float4*)&rowp[256 + h * 32 + c];
        *(float4*)&Vs[tid][c] = *(const float4*)&rowp[512 + h * 32 + c];
    }
    msk[tid] = mask[b * Nn + tid];
    float q[32];
#pragma unroll
    for (int c = 0; c < 32; c++) q[c] = rowp[h * 32 + c];
    __syncthreads();
    const float sc = 0.17677669529663687f;
    float mx = -3.0e38f;
    for (int m = 0; m < Nn; m++) {
        float s = 0.f;
#pragma unroll
        for (int c = 0; c < 32; c += 4) {
            float4 kv = *(const float4*)&Ks[m][c];
            s += q[c] * kv.x + q[c + 1] * kv.y + q[c + 2] * kv.z + q[c + 3] * kv.w;
        }
        s *= sc;
        s = msk[m] > 0.f ? s : -1.0e9f;
        mx = fmaxf(mx, s);
    }
    float l = 0.f;
    float o[32];
#pragma unroll
    for (int c = 0; c < 32; c++) o[c] = 0.f;
    for (int m = 0; m < Nn; m++) {
        float s = 0.f;
#pragma unroll
        for (int c = 0; c < 32; c += 4) {
            float4 kv = *(const float4*)&Ks[m][c];
            s += q[c] * kv.x + q[c + 1] * kv.y + q[c + 2] * kv.z + q[c + 3] * kv.w;
        }
        s *= sc;
        s = msk[m] > 0.f ? s : -1.0e9f;
        float p = __expf(s - mx);
        l += p;
#pragma unroll
        for (int c = 0; c < 32; c += 4) {
            float4 vv = *(const float4*)&Vs[m][c];
            o[c] += p * vv.x; o[c + 1] += p * vv.y; o[c + 2] += p * vv.z; o[c + 3] += p * vv.w;
        }
    }
    float inv = 1.f / l;
    float* op = outp + (size_t)(b * Nn + tid) * Dn + h * 32;
#pragma unroll
    for (int c = 0; c < 32; c += 4) {
        float4 v; v.x = o[c] * inv; v.y = o[c + 1] * inv; v.z = o[c + 2] * inv; v.w = o[c + 3] * inv;
        *(float4*)&op[c] = v;
    }
}

// ---------------- layernorm ----------------
template <bool PM>
__global__ __launch_bounds__(256) void k_ln(const float* __restrict__ res,
                                            const float* __restrict__ del,
                                            const float* __restrict__ g,
                                            const float* __restrict__ beta,
                                            const float* __restrict__ gamma,
                                            const float* __restrict__ mask,
                                            float* __restrict__ outp) {
    int wid = threadIdx.x >> 6, lane = threadIdx.x & 63;
    int t = blockIdx.x * 4 + wid;
    int c = lane << 2;
    float4 rv = *(const float4*)&res[(size_t)t * Dn + c];
    float4 dv = *(const float4*)&del[(size_t)t * Dn + c];
    float x0, x1, x2, x3;
    if (PM) {
        float m = mask[t];
        x0 = rv.x + dv.x * gamma[c + 0] * m;
        x1 = rv.y + dv.y * gamma[c + 1] * m;
        x2 = rv.z + dv.z * gamma[c + 2] * m;
        x3 = rv.w + dv.w * gamma[c + 3] * m;
    } else {
        x0 = rv.x + dv.x; x1 = rv.y + dv.y; x2 = rv.z + dv.z; x3 = rv.w + dv.w;
    }
    float s = x0 + x1 + x2 + x3;
#pragma unroll
    for (int off = 1; off < 64; off <<= 1) s += __shfl_xor(s, off, 64);
    float mean = s * (1.f / 256.f);
    float e0 = x0 - mean, e1 = x1 - mean, e2 = x2 - mean, e3 = x3 - mean;
    float qd = e0 * e0 + e1 * e1 + e2 * e2 + e3 * e3;
#pragma unroll
    for (int off = 1; off < 64; off <<= 1) qd += __shfl_xor(qd, off, 64);
    float rs = rsqrtf(qd * (1.f / 256.f) + 1e-5f);
    float4 ov;
    ov.x = e0 * rs * g[c + 0] + beta[c + 0];
    ov.y = e1 * rs * g[c + 1] + beta[c + 1];
    ov.z = e2 * rs * g[c + 2] + beta[c + 2];
    ov.w = e3 * rs * g[c + 3] + beta[c + 3];
    *(float4*)&outp[(size_t)t * Dn + c] = ov;
}

__global__ void k_out(const float* __restrict__ x, const float* __restrict__ skip,
                      float* __restrict__ o) {
    int gid = blockIdx.x * 256 + threadIdx.x;
    float4 a = *(const float4*)&x[(size_t)gid * 4];
    float4 b = *(const float4*)&skip[(size_t)gid * 4];
    float4 v; v.x = a.x + b.x; v.y = a.y + b.y; v.z = a.z + b.z; v.w = a.w + b.w;
    *(float4*)&o[(size_t)gid * 4] = v;
}

extern "C" void kernel_launch(void* const* d_in, const int* in_sizes, int n_in,
                              void* d_out, int out_size, void* d_ws, size_t ws_size,
                              hipStream_t stream) {
    (void)in_sizes; (void)n_in; (void)out_size; (void)d_ws; (void)ws_size;
    const float* f_feat = (const float*)d_in[0];
    const float* f_pts  = (const float*)d_in[1];
    const float* f_mask = (const float*)d_in[2];
    const float* f_time = (const float*)d_in[3];
    const float* enc_w1 = (const float*)d_in[4];
    const float* enc_b1 = (const float*)d_in[5];
    const float* enc_w2 = (const float*)d_in[6];
    const float* enc_b2 = (const float*)d_in[7];
    const float* four_w1 = (const float*)d_in[8];
    const float* four_w2 = (const float*)d_in[9];
    const float* time_w = (const float*)d_in[10];
    const float* l1w1 = (const float*)d_in[11];
    const float* l1b1 = (const float*)d_in[12];
    const float* l1w2 = (const float*)d_in[13];
    const float* l1b2 = (const float*)d_in[14];
    const float* l2w1 = (const float*)d_in[15];
    const float* l2b1 = (const float*)d_in[16];
    const float* l2w2 = (const float*)d_in[17];
    const float* l2b2 = (const float*)d_in[18];
    const float* qkv_w = (const float*)d_in[19];
    const float* qkv_b = (const float*)d_in[20];
    const float* out_w = (const float*)d_in[21];
    const float* out_b = (const float*)d_in[22];
    const float* ln1g = (const float*)d_in[23];
    const float* ln1b = (const float*)d_in[24];
    const float* ff1w = (const float*)d_in[25];
    const float* ff1b = (const float*)d_in[26];
    const float* ff2w = (const float*)d_in[27];
    const float* ff2b = (const float*)d_in[28];
    const float* gam  = (const float*)d_in[29];
    const float* ln2g = (const float*)d_in[30];
    const float* ln2b = (const float*)d_in[31];
    float* out = (float*)d_out;

    float *big, *x, *skip, *lf1, *lf2, *attn, *u, *r, *h2;
    int* idx;
    unsigned short *loc, *h1, *wt;
    hipGetSymbolAddress((void**)&big,  HIP_SYMBOL(g_big));
    hipGetSymbolAddress((void**)&x,    HIP_SYMBOL(g_x));
    hipGetSymbolAddress((void**)&skip, HIP_SYMBOL(g_skip));
    hipGetSymbolAddress((void**)&lf1,  HIP_SYMBOL(g_lf1));
    hipGetSymbolAddress((void**)&lf2,  HIP_SYMBOL(g_lf2));
    hipGetSymbolAddress((void**)&attn, HIP_SYMBOL(g_attn));
    hipGetSymbolAddress((void**)&u,    HIP_SYMBOL(g_u));
    hipGetSymbolAddress((void**)&r,    HIP_SYMBOL(g_r));
    hipGetSymbolAddress((void**)&idx,  HIP_SYMBOL(g_idx));
    hipGetSymbolAddress((void**)&loc,  HIP_SYMBOL(g_loc));
    hipGetSymbolAddress((void**)&h1,   HIP_SYMBOL(g_h1));
    hipGetSymbolAddress((void**)&h2,   HIP_SYMBOL(g_h2));
    hipGetSymbolAddress((void**)&wt,   HIP_SYMBOL(g_wt));

    // ---- weight prep (bf16 transpose) ----
    k_prep<<<dim3(8, 16, 1), 256, 0, stream>>>(enc_w2, wt + OFF_ENC2, 512, 512, 256, 0, 0);
    k_prep<<<dim3(16, 1, 1), 256, 0, stream>>>(l1w1, wt + OFF_L1W1, 26, 32, 512, 0, 0);
    k_prep<<<dim3(8, 16, 1), 256, 0, stream>>>(l1w2, wt + OFF_L1W2, 512, 512, 256, 0, 0);
    k_prep<<<dim3(16, 16, 1), 256, 0, stream>>>(l2w1, wt + OFF_L2W1, 512, 512, 512, 0, 0);
    k_prep<<<dim3(8, 16, 1), 256, 0, stream>>>(l2w2, wt + OFF_L2W2, 512, 512, 256, 0, 0);
    k_prep<<<dim3(24, 8, 8), 256, 0, stream>>>(qkv_w, wt + OFF_QKV, 256, 256, 768, 256 * 768, 768 * 256);
    k_prep<<<dim3(8, 8, 8), 256, 0, stream>>>(out_w, wt + OFF_OUT, 256, 256, 256, 256 * 256, 256 * 256);
    k_prep<<<dim3(16, 8, 8), 256, 0, stream>>>(ff1w, wt + OFF_FF1, 256, 256, 512, 256 * 512, 512 * 256);
    k_prep<<<dim3(8, 16, 8), 256, 0, stream>>>(ff2w, wt + OFF_FF2, 512, 512, 256, 512 * 256, 256 * 512);

    // ---- time embedding ----
    k_time<<<Bn, 256, 0, stream>>>(f_time, four_w1, four_w2, time_w, u);
    // ---- encoder ----
    k_enc1<<<Tn, 256, 0, stream>>>(f_feat, enc_w1, enc_b1, big);
    k_mgemm<false, 1, false><<<dim3(2, 128), 256, 0, stream>>>(big, wt + OFF_ENC2, enc_b2, x, 512, 256);
    // ---- knn pass 1 ----
    k_topk2<<<Bn, Nn, 0, stream>>>(f_pts, f_mask, idx);
    k_gather1<<<Tn, 256, 0, stream>>>(f_feat, idx, loc);
    k_mgemm<true, 1, true><<<dim3(4, 1280), 256, 0, stream>>>(loc, wt + OFF_L1W1, l1b1, h1, 32, 512);
    k_mgemm<true, 1, false><<<dim3(2, 1280), 256, 0, stream>>>(h1, wt + OFF_L1W2, l1b2, h2, 512, 256);
    k_mean<<<Tn, 256, 0, stream>>>(h2, lf1);
    // ---- knn pass 2 ----
    k_shift<<<Tn * Dn / 256, 256, 0, stream>>>(lf1, f_mask, big);
    k_rnorm<<<Tn, 64, 0, stream>>>(big, r);
    k_dist<<<dim3(2, 2, Bn), 256, 0, stream>>>(big, r, attn);
    k_topkg<<<Bn, Nn, 0, stream>>>(attn, idx);
    k_gather2<<<Rn, 256, 0, stream>>>(lf1, idx, loc);
    k_mgemm<true, 1, true><<<dim3(4, 1280), 256, 0, stream>>>(loc, wt + OFF_L2W1, l2b1, h1, 512, 512);
    k_mgemm<true, 1, false><<<dim3(2, 1280), 256, 0, stream>>>(h1, wt + OFF_L2W2, l2b2, h2, 512, 256);
    k_mean<<<Tn, 256, 0, stream>>>(h2, lf2);
    // ---- combine ----
    k_combine<<<Tn * 64 / 256, 256, 0, stream>>>(u, f_mask, lf2, x, skip);
    // ---- transformer layers ----
    for (int l = 0; l < Ln; l++) {
        k_mgemm<false, 0, false><<<dim3(6, 128), 256, 0, stream>>>(
            x, wt + OFF_QKV + (size_t)l * 768 * 256, qkv_b + l * 768, big, 256, 768);
        k_attn<<<Bn * Hn, 128, 0, stream>>>(big, f_mask, attn);
        k_mgemm<false, 0, false><<<dim3(2, 128), 256, 0, stream>>>(
            attn, wt + OFF_OUT + (size_t)l * 256 * 256, out_b + l * 256, lf1, 256, 256);
        k_ln<false><<<Tn / 4, 256, 0, stream>>>(x, lf1, ln1g + l * Dn, ln1b + l * Dn, nullptr, f_mask, x);
        k_mgemm<false, 1, false><<<dim3(4, 128), 256, 0, stream>>>(
            x, wt + OFF_FF1 + (size_t)l * 512 * 256, ff1b + l * 512, big, 256, 512);
        k_mgemm<false, 0, false><<<dim3(2, 128), 256, 0, stream>>>(
            big, wt + OFF_FF2 + (size_t)l * 256 * 512, ff2b + l * 256, lf2, 512, 256);
        k_ln<true><<<Tn / 4, 256, 0, stream>>>(x, lf2, ln2g + l * Dn, ln2b + l * Dn, gam + l * Dn, f_mask, x);
    }
    // ---- final residual ----
    k_out<<<Tn * 64 / 256, 256, 0, stream>>>(x, skip, out);
}

// Round 3
// 2331.051 us; speedup vs baseline: 6.9907x; 1.2623x over previous
//
#include <hip/hip_runtime.h>
#include <cmath>

#define DEV_INLINE __device__ __forceinline__

constexpr int Bn = 128;
constexpr int Nn = 128;
constexpr int Fn = 13;
constexpr int Dn = 256;
constexpr int Ln = 8;
constexpr int Kn = 10;
constexpr int FFn = 512;
constexpr int Tn = Bn * Nn;   // 16384
constexpr int Rn = Tn * Kn;   // 163840

typedef __attribute__((ext_vector_type(4))) float f32x4;
typedef __attribute__((ext_vector_type(8))) short bf16x8;
typedef unsigned short us;

// ---------------- static device workspace ----------------
__device__ float g_x[Tn * Dn];
__device__ float g_skip[Tn * Dn];
__device__ float g_lf1[Tn * Dn];
__device__ float g_lf2[Tn * Dn];
__device__ float g_dm[Tn * Nn];      // distance matrix
__device__ float g_big[Tn * Dn];     // shifted lf1 (f32, exact distances)
__device__ float g_u[Bn * FFn];
__device__ float g_r[Tn];
__device__ float g_pqbias[2048];
__device__ int   g_idx[Rn];
__device__ us g_bigb[Tn * 768];      // enc hidden / qkv / ffn hidden (bf16)
__device__ us g_xb[Tn * Dn];
__device__ us g_attb[Tn * Dn];
__device__ us g_lf1b[Tn * Dn];
__device__ us g_pq[Tn * 1024];       // P|Q per token (bf16)
__device__ us g_h2b[Rn * Dn];        // knn h2 pre-mean (bf16)
__device__ us g_feat16[Tn * 32];     // padded bf16 features
// transposed bf16 weights [N][Kpad]
constexpr int OFF_ENC2 = 0;
constexpr int OFF_W2A  = OFF_ENC2 + 256 * 512;
constexpr int OFF_W2B  = OFF_W2A + 256 * 512;
constexpr int OFF_PQ1  = OFF_W2B + 256 * 512;
constexpr int OFF_PQ2  = OFF_PQ1 + 1024 * 32;
constexpr int OFF_QKV  = OFF_PQ2 + 1024 * 256;
constexpr int OFF_OUT  = OFF_QKV + 8 * 768 * 256;
constexpr int OFF_FF1  = OFF_OUT + 8 * 256 * 256;
constexpr int OFF_FF2  = OFF_FF1 + 8 * 512 * 256;
constexpr int WT_TOTAL = OFF_FF2 + 8 * 256 * 512;
__device__ us g_wt[WT_TOTAL];

DEV_INLINE float gelu_f(float x) {
    float u = 0.7978845608028654f * (x + 0.044715f * x * x * x);
    return 0.5f * x * (1.f + tanhf(u));
}
DEV_INLINE us f2b(float x) {
    unsigned int u = __float_as_uint(x);
    u += 0x7FFFu + ((u >> 16) & 1u);
    return (us)(u >> 16);
}
DEV_INLINE float blo(unsigned u) { return __uint_as_float(u << 16); }
DEV_INLINE float bhi(unsigned u) { return __uint_as_float(u & 0xFFFF0000u); }
DEV_INLINE unsigned pk2(float a, float b) { return (unsigned)f2b(a) | ((unsigned)f2b(b) << 16); }

#define GLOAD16(gp, lp)                                                            \
    __builtin_amdgcn_global_load_lds(                                              \
        (const __attribute__((address_space(1))) unsigned int*)(gp),               \
        (__attribute__((address_space(3))) unsigned int*)(lp), 16, 0, 0)

// ---------------- weight prep: f32 [K][N] -> bf16 [N][Kpad] ----------------
__global__ __launch_bounds__(256) void k_prep(const float* __restrict__ src,
                                              us* __restrict__ dst,
                                              int Kreal, int Kpad, int Nd,
                                              long sstride, long dstride) {
    __shared__ float tile[32][33];
    int l = blockIdx.z;
    const float* s = src + (size_t)l * sstride;
    us* d = dst + (size_t)l * dstride;
    int tid = threadIdx.x;
    int cn = tid & 31, rk = tid >> 5;
    int kbase = blockIdx.y * 32, nbase = blockIdx.x * 32;
#pragma unroll
    for (int p = 0; p < 4; p++) {
        int k = kbase + p * 8 + rk;
        float v = (k < Kreal) ? s[(size_t)k * Nd + nbase + cn] : 0.f;
        tile[p * 8 + rk][cn] = v;
    }
    __syncthreads();
#pragma unroll
    for (int p = 0; p < 4; p++) {
        int nl = p * 8 + rk;
        d[(size_t)(nbase + nl) * Kpad + kbase + cn] = f2b(tile[cn][nl]);
    }
}

// ---- PQ weight prep: w1 [2K][512] -> [1024][Kpad] bf16 ([w1a | w1b-w1a]^T), bias [1024] ----
__global__ void k_prepPQ(const float* __restrict__ w1, const float* __restrict__ b1,
                         us* __restrict__ dst, float* __restrict__ bdst,
                         int Kreal, int Kpad) {
    int n = blockIdx.x;
    for (int k = threadIdx.x; k < Kpad; k += blockDim.x) {
        float v;
        if (n < 512) v = (k < Kreal) ? w1[(size_t)k * 512 + n] : 0.f;
        else {
            int m = n - 512;
            v = (k < Kreal) ? (w1[(size_t)(Kreal + k) * 512 + m] - w1[(size_t)k * 512 + m]) : 0.f;
        }
        dst[(size_t)n * Kpad + k] = f2b(v);
    }
    if (threadIdx.x == 0) bdst[n] = (n < 512) ? 0.f : b1[n - 512];
}

__global__ void k_featpad(const float* __restrict__ feat, us* __restrict__ fp) {
    int gid = blockIdx.x * 256 + threadIdx.x;
    int t = gid >> 5, c = gid & 31;
    fp[gid] = (c < Fn) ? f2b(feat[(size_t)t * Fn + c]) : (us)0;
}

// ---------------- MFMA GEMM (m97 structure): C = epi(A @ Bt^T + bias) ----------------
// A bf16 [M][Kd], Bt bf16 [Nd][Kd]. 128x128 tile, BK=32, 256 thr, global_load_lds staging.
template <int EPI, bool OBF>
__global__ __launch_bounds__(256) void k_mg2(const us* __restrict__ A,
                                             const us* __restrict__ Bt,
                                             const float* __restrict__ bias,
                                             void* __restrict__ Cp,
                                             int Kd, int Nd) {
    __shared__ __align__(16) us As[128 * 32];
    __shared__ __align__(16) us Bs[128 * 32];
    int tid = threadIdx.x;
    int m0 = blockIdx.y << 7, n0 = blockIdx.x << 7;
    int wave = tid >> 6, lane = tid & 63;
    int wm = (wave & 1) << 6, wn = (wave >> 1) << 6;
    int lm = lane & 15, quad = lane >> 4;
    // staging: wave covers rows [wave*32, wave*32+32); lane: row += lane/4, col = (lane&3)*8
    int r0 = (wave << 5) + (lane >> 2);
    int colu = (lane & 3) << 3;
    const us* pa0 = A + (size_t)(m0 + r0) * Kd + colu;
    const us* pa1 = A + (size_t)(m0 + r0 + 16) * Kd + colu;
    const us* pb0 = Bt + (size_t)(n0 + r0) * Kd + colu;
    const us* pb1 = Bt + (size_t)(n0 + r0 + 16) * Kd + colu;
    auto lAs = (__attribute__((address_space(3))) us*)As;
    auto lBs = (__attribute__((address_space(3))) us*)Bs;
    int lbase = wave << 10; // wave*2 segments * 512 ushorts
    f32x4 acc[4][4] = {};
    for (int k0 = 0; k0 < Kd; k0 += 32) {
        __syncthreads();
        GLOAD16(pa0 + k0, lAs + lbase);
        GLOAD16(pa1 + k0, lAs + lbase + 512);
        GLOAD16(pb0 + k0, lBs + lbase);
        GLOAD16(pb1 + k0, lBs + lbase + 512);
        __syncthreads();
        bf16x8 afr[4], bfr[4];
#pragma unroll
        for (int i = 0; i < 4; i++) {
            afr[i] = *(const bf16x8*)&As[(wm + i * 16 + lm) * 32 + (quad << 3)];
            bfr[i] = *(const bf16x8*)&Bs[(wn + i * 16 + lm) * 32 + (quad << 3)];
        }
#pragma unroll
        for (int mf = 0; mf < 4; mf++)
#pragma unroll
            for (int nf = 0; nf < 4; nf++)
                acc[mf][nf] = __builtin_amdgcn_mfma_f32_16x16x32_bf16(afr[mf], bfr[nf], acc[mf][nf], 0, 0, 0);
    }
    float bvs[4];
#pragma unroll
    for (int nf = 0; nf < 4; nf++) bvs[nf] = bias[n0 + wn + nf * 16 + lm];
#pragma unroll
    for (int mf = 0; mf < 4; mf++) {
#pragma unroll
        for (int r = 0; r < 4; r++) {
            size_t row = (size_t)(m0 + wm + mf * 16 + (quad << 2) + r);
#pragma unroll
            for (int nf = 0; nf < 4; nf++) {
                float v = acc[mf][nf][r] + bvs[nf];
                if (EPI == 1) v = gelu_f(v);
                size_t ci = row * Nd + n0 + wn + nf * 16 + lm;
                if constexpr (OBF) ((us*)Cp)[ci] = f2b(v);
                else ((float*)Cp)[ci] = v;
            }
        }
    }
}

// ---------------- fused KNN GEMM2: h2 = gelu(gelu(P[nb]+Q[t]) @ w2t^T + b2) ----------------
// M=163840 rows (r=t*10+k), N=256 full width per block, K=512. 512 threads (8 waves).
__global__ __launch_bounds__(512) void k_knng(const us* __restrict__ pq,
                                              const int* __restrict__ idx,
                                              const us* __restrict__ Bt,   // [256][512]
                                              const float* __restrict__ bias,
                                              us* __restrict__ h2b) {
    __shared__ __align__(16) us As[128 * 32];
    __shared__ __align__(16) us Bs[256 * 32];
    int tid = threadIdx.x;
    int m0 = blockIdx.x << 7;
    int wave = tid >> 6, lane = tid & 63;
    int wm = (wave & 1) << 6, wn = (wave >> 1) << 6;
    int lm = lane & 15, quad = lane >> 4;
    // A staging (VALU h1): thread -> row tid/4, col (tid&3)*8
    int arow = tid >> 2, acolu = (tid & 3) << 3;
    int r = m0 + arow;
    int tok = r / 10;
    int nb = idx[r];
    int prow = (tok & ~127) + nb;
    const us* Pp = pq + (size_t)prow * 1024 + acolu;
    const us* Qp = pq + (size_t)tok * 1024 + 512 + acolu;
    // B staging via global_load_lds: 8 waves x 2 segs x 16 rows = 256 rows
    int r0 = (wave << 5) + (lane >> 2);
    int colu = (lane & 3) << 3;
    const us* pb0 = Bt + (size_t)r0 * 512 + colu;
    const us* pb1 = Bt + (size_t)(r0 + 16) * 512 + colu;
    auto lBs = (__attribute__((address_space(3))) us*)Bs;
    int lbase = wave << 10;
    f32x4 acc[4][4] = {};
    for (int k0 = 0; k0 < 512; k0 += 32) {
        uint4 pv = *(const uint4*)(Pp + k0);
        uint4 qv = *(const uint4*)(Qp + k0);
        uint4 hv;
        hv.x = pk2(gelu_f(blo(pv.x) + blo(qv.x)), gelu_f(bhi(pv.x) + bhi(qv.x)));
        hv.y = pk2(gelu_f(blo(pv.y) + blo(qv.y)), gelu_f(bhi(pv.y) + bhi(qv.y)));
        hv.z = pk2(gelu_f(blo(pv.z) + blo(qv.z)), gelu_f(bhi(pv.z) + bhi(qv.z)));
        hv.w = pk2(gelu_f(blo(pv.w) + blo(qv.w)), gelu_f(bhi(pv.w) + bhi(qv.w)));
        __syncthreads();
        GLOAD16(pb0 + k0, lBs + lbase);
        GLOAD16(pb1 + k0, lBs + lbase + 512);
        *(uint4*)&As[arow * 32 + acolu] = hv;
        __syncthreads();
        bf16x8 afr[4], bfr[4];
#pragma unroll
        for (int i = 0; i < 4; i++) {
            afr[i] = *(const bf16x8*)&As[(wm + i * 16 + lm) * 32 + (quad << 3)];
            bfr[i] = *(const bf16x8*)&Bs[(wn + i * 16 + lm) * 32 + (quad << 3)];
        }
#pragma unroll
        for (int mf = 0; mf < 4; mf++)
#pragma unroll
            for (int nf = 0; nf < 4; nf++)
                acc[mf][nf] = __builtin_amdgcn_mfma_f32_16x16x32_bf16(afr[mf], bfr[nf], acc[mf][nf], 0, 0, 0);
    }
    float bvs[4];
#pragma unroll
    for (int nf = 0; nf < 4; nf++) bvs[nf] = bias[wn + nf * 16 + lm];
#pragma unroll
    for (int mf = 0; mf < 4; mf++) {
#pragma unroll
        for (int rr = 0; rr < 4; rr++) {
            size_t row = (size_t)(m0 + wm + mf * 16 + (quad << 2) + rr);
#pragma unroll
            for (int nf = 0; nf < 4; nf++) {
                float v = gelu_f(acc[mf][nf][rr] + bvs[nf]);
                h2b[row * 256 + wn + nf * 16 + lm] = f2b(v);
            }
        }
    }
}

__global__ __launch_bounds__(256) void k_mean(const us* __restrict__ h2b,
                                              float* __restrict__ lf, us* __restrict__ lfb) {
    int t = blockIdx.x, c = threadIdx.x;
    const us* p = h2b + (size_t)t * Kn * 256 + c;
    float s = 0.f;
#pragma unroll
    for (int k = 0; k < Kn; k++) s += blo((unsigned)p[k * 256]);
    s *= 0.1f;
    lf[(size_t)t * 256 + c] = s;
    if (lfb) lfb[(size_t)t * 256 + c] = f2b(s);
}

// ---------------- time / fourier MLP ----------------
__global__ __launch_bounds__(256) void k_time(const float* __restrict__ tin,
                                              const float* __restrict__ w1,
                                              const float* __restrict__ w2,
                                              const float* __restrict__ tw,
                                              float* __restrict__ u) {
    __shared__ float e[256], e1[512], t2[256];
    int b = blockIdx.x, tid = threadIdx.x;
    float tv = tin[b];
    if (tid < 128) {
        const float emb = 0.07252236513366287f;
        float fr = expf(-emb * (float)tid);
        float ang = tv * fr * 1000.f;
        e[tid] = sinf(ang);
        e[tid + 128] = cosf(ang);
    }
    __syncthreads();
    for (int j = tid; j < 512; j += 256) {
        float s = 0.f;
        for (int i = 0; i < 256; i++) s += e[i] * w1[(size_t)i * 512 + j];
        e1[j] = s / (1.f + expf(-s));
    }
    __syncthreads();
    {
        float s = 0.f;
        for (int i = 0; i < 512; i++) s += e1[i] * w2[(size_t)i * 256 + tid];
        t2[tid] = s / (1.f + expf(-s));
    }
    __syncthreads();
    for (int j = tid; j < 512; j += 256) {
        float s = 0.f;
        for (int i = 0; i < 256; i++) s += t2[i] * tw[(size_t)i * 512 + j];
        u[(size_t)b * 512 + j] = s;
    }
}

// ---------------- encoder stage 1 (K=13) -> bf16 ----------------
__global__ __launch_bounds__(256) void k_enc1(const float* __restrict__ feat,
                                              const float* __restrict__ w1,
                                              const float* __restrict__ b1,
                                              us* __restrict__ Hb) {
    __shared__ float f[16];
    int t = blockIdx.x, tid = threadIdx.x;
    if (tid < Fn) f[tid] = feat[(size_t)t * Fn + tid];
    __syncthreads();
    for (int j = tid; j < FFn; j += 256) {
        float s = b1[j];
#pragma unroll
        for (int i = 0; i < Fn; i++) s += f[i] * w1[(size_t)i * FFn + j];
        Hb[(size_t)t * FFn + j] = f2b(gelu_f(s));
    }
}

// ---------------- knn top-k on 2-d points ----------------
__global__ __launch_bounds__(128) void k_topk2(const float* __restrict__ pts,
                                               const float* __restrict__ mask,
                                               int* __restrict__ idx) {
    int b = blockIdx.x, n = threadIdx.x;
    __shared__ float px[Nn], py[Nn], rr[Nn];
    float shift = 999.f * (1.f - mask[b * Nn + n]);
    float x = pts[(size_t)(b * Nn + n) * 2 + 0] + shift;
    float y = pts[(size_t)(b * Nn + n) * 2 + 1] + shift;
    px[n] = x; py[n] = y; rr[n] = x * x + y * y;
    __syncthreads();
    float rn = rr[n];
    float bd[Kn + 1]; int bi[Kn + 1];
#pragma unroll
    for (int j = 0; j <= Kn; j++) { bd[j] = 3.4e38f; bi[j] = -1; }
    for (int m = 0; m < Nn; m++) {
        float d = rn - 2.f * (x * px[m] + y * py[m]) + rr[m];
        if (d < bd[Kn]) {
            int j = Kn;
            while (j > 0 && d < bd[j - 1]) { bd[j] = bd[j - 1]; bi[j] = bi[j - 1]; j--; }
            bd[j] = d; bi[j] = m;
        }
    }
    for (int j = 1; j <= Kn; j++) idx[(size_t)(b * Nn + n) * Kn + j - 1] = bi[j];
}

__global__ void k_shift(const float* __restrict__ lf, const float* __restrict__ mask,
                        float* __restrict__ o) {
    int gid = blockIdx.x * 256 + threadIdx.x;
    int t = gid >> 8;
    o[gid] = lf[gid] + 999.f * (1.f - mask[t]);
}

__global__ __launch_bounds__(64) void k_rnorm(const float* __restrict__ fe, float* __restrict__ r) {
    int t = blockIdx.x, lane = threadIdx.x;
    const float* p = fe + (size_t)t * Dn;
    float s = 0.f;
    for (int i = lane; i < Dn; i += 64) { float v = p[i]; s += v * v; }
#pragma unroll
    for (int off = 32; off; off >>= 1) s += __shfl_xor(s, off, 64);
    if (lane == 0) r[t] = s;
}

__global__ __launch_bounds__(256) void k_dist(const float* __restrict__ fe,
                                              const float* __restrict__ r,
                                              float* __restrict__ Dm) {
    int b = blockIdx.z;
    int m0 = blockIdx.x * 64, n0 = blockIdx.y * 64;
    const float* A = fe + (size_t)b * Nn * Dn;
    __shared__ float As[16][68];
    __shared__ float Bs[16][68];
    int tid = threadIdx.x;
    int tx = tid & 15, ty = tid >> 4;
    int ar = tid >> 2, ac = (tid & 3) << 2;
    float acc[4][4] = {};
    for (int k0 = 0; k0 < Dn; k0 += 16) {
        float4 av = *(const float4*)&A[(size_t)(n0 + ar) * Dn + k0 + ac];
        float4 bv = *(const float4*)&A[(size_t)(m0 + ar) * Dn + k0 + ac];
        __syncthreads();
        As[ac + 0][ar] = av.x; As[ac + 1][ar] = av.y; As[ac + 2][ar] = av.z; As[ac + 3][ar] = av.w;
        Bs[ac + 0][ar] = bv.x; Bs[ac + 1][ar] = bv.y; Bs[ac + 2][ar] = bv.z; Bs[ac + 3][ar] = bv.w;
        __syncthreads();
#pragma unroll
        for (int kk = 0; kk < 16; kk++) {
            float4 a = *(const float4*)&As[kk][ty << 2];
            float4 b2 = *(const float4*)&Bs[kk][tx << 2];
            acc[0][0] += a.x * b2.x; acc[0][1] += a.x * b2.y; acc[0][2] += a.x * b2.z; acc[0][3] += a.x * b2.w;
            acc[1][0] += a.y * b2.x; acc[1][1] += a.y * b2.y; acc[1][2] += a.y * b2.z; acc[1][3] += a.y * b2.w;
            acc[2][0] += a.z * b2.x; acc[2][1] += a.z * b2.y; acc[2][2] += a.z * b2.z; acc[2][3] += a.z * b2.w;
            acc[3][0] += a.w * b2.x; acc[3][1] += a.w * b2.y; acc[3][2] += a.w * b2.z; acc[3][3] += a.w * b2.w;
        }
    }
    float4 rm = *(const float4*)&r[b * Nn + m0 + (tx << 2)];
#pragma unroll
    for (int i = 0; i < 4; i++) {
        int n = n0 + (ty << 2) + i;
        float rn = r[b * Nn + n];
        float4 v;
        v.x = rn - 2.f * acc[i][0] + rm.x;
        v.y = rn - 2.f * acc[i][1] + rm.y;
        v.z = rn - 2.f * acc[i][2] + rm.z;
        v.w = rn - 2.f * acc[i][3] + rm.w;
        *(float4*)&Dm[(size_t)b * Nn * Nn + (size_t)n * Nn + m0 + (tx << 2)] = v;
    }
}

__global__ __launch_bounds__(128) void k_topkg(const float* __restrict__ Dm, int* __restrict__ idx) {
    int b = blockIdx.x, n = threadIdx.x;
    const float* row = Dm + (size_t)b * Nn * Nn + (size_t)n * Nn;
    float bd[Kn + 1]; int bi[Kn + 1];
#pragma unroll
    for (int j = 0; j <= Kn; j++) { bd[j] = 3.4e38f; bi[j] = -1; }
    for (int m = 0; m < Nn; m++) {
        float d = row[m];
        if (d < bd[Kn]) {
            int j = Kn;
            while (j > 0 && d < bd[j - 1]) { bd[j] = bd[j - 1]; bi[j] = bi[j - 1]; j--; }
            bd[j] = d; bi[j] = m;
        }
    }
    for (int j = 1; j <= Kn; j++) idx[(size_t)(b * Nn + n) * Kn + j - 1] = bi[j];
}

// ---------------- combine: x = enc*(1+m*sc) + m*sh + lf2 ; also skip, xb ----------------
__global__ void k_combine(const float* __restrict__ u, const float* __restrict__ mask,
                          const float* __restrict__ lf2, float* __restrict__ x,
                          float* __restrict__ skip, us* __restrict__ xb) {
    int gid = blockIdx.x * 256 + threadIdx.x;
    int t = gid >> 6;
    int c = (gid & 63) << 2;
    int b = t >> 7;
    float m = mask[t];
    float4 xv = *(const float4*)&x[(size_t)t * Dn + c];
    float4 lv = *(const float4*)&lf2[(size_t)t * Dn + c];
    float4 sc = *(const float4*)&u[(size_t)b * 512 + c];
    float4 sh = *(const float4*)&u[(size_t)b * 512 + 256 + c];
    float4 v;
    v.x = xv.x * (1.f + m * sc.x) + m * sh.x + lv.x;
    v.y = xv.y * (1.f + m * sc.y) + m * sh.y + lv.y;
    v.z = xv.z * (1.f + m * sc.z) + m * sh.z + lv.z;
    v.w = xv.w * (1.f + m * sc.w) + m * sh.w + lv.w;
    *(float4*)&x[(size_t)t * Dn + c] = v;
    *(float4*)&skip[(size_t)t * Dn + c] = v;
    uint2 p; p.x = pk2(v.x, v.y); p.y = pk2(v.z, v.w);
    *(uint2*)&xb[(size_t)t * Dn + c] = p;
}

// ---------------- attention (bf16 in/out) ----------------
__global__ __launch_bounds__(128) void k_attn(const us* __restrict__ qkv,
                                              const float* __restrict__ mask,
                                              us* __restrict__ outp) {
    int bh = blockIdx.x;
    int b = bh >> 3, h = bh & 7;
    __shared__ float Ks[Nn][36], Vs[Nn][36], msk[Nn];
    int tid = threadIdx.x;
    const us* rowp = qkv + (size_t)(b * Nn + tid) * 768;
#pragma unroll
    for (int c = 0; c < 32; c += 8) {
        uint4 kv = *(const uint4*)&rowp[256 + h * 32 + c];
        uint4 vv = *(const uint4*)&rowp[512 + h * 32 + c];
        Ks[tid][c + 0] = blo(kv.x); Ks[tid][c + 1] = bhi(kv.x);
        Ks[tid][c + 2] = blo(kv.y); Ks[tid][c + 3] = bhi(kv.y);
        Ks[tid][c + 4] = blo(kv.z); Ks[tid][c + 5] = bhi(kv.z);
        Ks[tid][c + 6] = blo(kv.w); Ks[tid][c + 7] = bhi(kv.w);
        Vs[tid][c + 0] = blo(vv.x); Vs[tid][c + 1] = bhi(vv.x);
        Vs[tid][c + 2] = blo(vv.y); Vs[tid][c + 3] = bhi(vv.y);
        Vs[tid][c + 4] = blo(vv.z); Vs[tid][c + 5] = bhi(vv.z);
        Vs[tid][c + 6] = blo(vv.w); Vs[tid][c + 7] = bhi(vv.w);
    }
    msk[tid] = mask[b * Nn + tid];
    float q[32];
#pragma unroll
    for (int c = 0; c < 32; c += 8) {
        uint4 qv = *(const uint4*)&rowp[h * 32 + c];
        q[c + 0] = blo(qv.x); q[c + 1] = bhi(qv.x);
        q[c + 2] = blo(qv.y); q[c + 3] = bhi(qv.y);
        q[c + 4] = blo(qv.z); q[c + 5] = bhi(qv.z);
        q[c + 6] = blo(qv.w); q[c + 7] = bhi(qv.w);
    }
    __syncthreads();
    const float sc = 0.17677669529663687f;
    float mx = -3.0e38f;
    for (int m = 0; m < Nn; m++) {
        float s = 0.f;
#pragma unroll
        for (int c = 0; c < 32; c += 4) {
            float4 kv = *(const float4*)&Ks[m][c];
            s += q[c] * kv.x + q[c + 1] * kv.y + q[c + 2] * kv.z + q[c + 3] * kv.w;
        }
        s *= sc;
        s = msk[m] > 0.f ? s : -1.0e9f;
        mx = fmaxf(mx, s);
    }
    float l = 0.f;
    float o[32];
#pragma unroll
    for (int c = 0; c < 32; c++) o[c] = 0.f;
    for (int m = 0; m < Nn; m++) {
        float s = 0.f;
#pragma unroll
        for (int c = 0; c < 32; c += 4) {
            float4 kv = *(const float4*)&Ks[m][c];
            s += q[c] * kv.x + q[c + 1] * kv.y + q[c + 2] * kv.z + q[c + 3] * kv.w;
        }
        s *= sc;
        s = msk[m] > 0.f ? s : -1.0e9f;
        float p = __expf(s - mx);
        l += p;
#pragma unroll
        for (int c = 0; c < 32; c += 4) {
            float4 vv = *(const float4*)&Vs[m][c];
            o[c] += p * vv.x; o[c + 1] += p * vv.y; o[c + 2] += p * vv.z; o[c + 3] += p * vv.w;
        }
    }
    float inv = 1.f / l;
    us* op = outp + (size_t)(b * Nn + tid) * Dn + h * 32;
#pragma unroll
    for (int c = 0; c < 32; c += 8) {
        uint4 v;
        v.x = pk2(o[c + 0] * inv, o[c + 1] * inv);
        v.y = pk2(o[c + 2] * inv, o[c + 3] * inv);
        v.z = pk2(o[c + 4] * inv, o[c + 5] * inv);
        v.w = pk2(o[c + 6] * inv, o[c + 7] * inv);
        *(uint4*)&op[c] = v;
    }
}

// ---------------- layernorm: out = LN(res + delta[*gamma*mask]) * g + beta ; + bf16 copy ----------------
template <bool PM>
__global__ __launch_bounds__(256) void k_ln(const float* __restrict__ res,
                                            const float* __restrict__ del,
                                            const float* __restrict__ g,
                                            const float* __restrict__ beta,
                                            const float* __restrict__ gamma,
                                            const float* __restrict__ mask,
                                            float* __restrict__ outp,
                                            us* __restrict__ outb) {
    int wid = threadIdx.x >> 6, lane = threadIdx.x & 63;
    int t = blockIdx.x * 4 + wid;
    int c = lane << 2;
    float4 rv = *(const float4*)&res[(size_t)t * Dn + c];
    float4 dv = *(const float4*)&del[(size_t)t * Dn + c];
    float x0, x1, x2, x3;
    if (PM) {
        float m = mask[t];
        x0 = rv.x + dv.x * gamma[c + 0] * m;
        x1 = rv.y + dv.y * gamma[c + 1] * m;
        x2 = rv.z + dv.z * gamma[c + 2] * m;
        x3 = rv.w + dv.w * gamma[c + 3] * m;
    } else {
        x0 = rv.x + dv.x; x1 = rv.y + dv.y; x2 = rv.z + dv.z; x3 = rv.w + dv.w;
    }
    float s = x0 + x1 + x2 + x3;
#pragma unroll
    for (int off = 1; off < 64; off <<= 1) s += __shfl_xor(s, off, 64);
    float mean = s * (1.f / 256.f);
    float e0 = x0 - mean, e1 = x1 - mean, e2 = x2 - mean, e3 = x3 - mean;
    float qd = e0 * e0 + e1 * e1 + e2 * e2 + e3 * e3;
#pragma unroll
    for (int off = 1; off < 64; off <<= 1) qd += __shfl_xor(qd, off, 64);
    float rs = rsqrtf(qd * (1.f / 256.f) + 1e-5f);
    float4 ov;
    ov.x = e0 * rs * g[c + 0] + beta[c + 0];
    ov.y = e1 * rs * g[c + 1] + beta[c + 1];
    ov.z = e2 * rs * g[c + 2] + beta[c + 2];
    ov.w = e3 * rs * g[c + 3] + beta[c + 3];
    *(float4*)&outp[(size_t)t * Dn + c] = ov;
    uint2 p; p.x = pk2(ov.x, ov.y); p.y = pk2(ov.z, ov.w);
    *(uint2*)&outb[(size_t)t * Dn + c] = p;
}

__global__ void k_out(const float* __restrict__ x, const float* __restrict__ skip,
                      float* __restrict__ o) {
    int gid = blockIdx.x * 256 + threadIdx.x;
    float4 a = *(const float4*)&x[(size_t)gid * 4];
    float4 b = *(const float4*)&skip[(size_t)gid * 4];
    float4 v; v.x = a.x + b.x; v.y = a.y + b.y; v.z = a.z + b.z; v.w = a.w + b.w;
    *(float4*)&o[(size_t)gid * 4] = v;
}

extern "C" void kernel_launch(void* const* d_in, const int* in_sizes, int n_in,
                              void* d_out, int out_size, void* d_ws, size_t ws_size,
                              hipStream_t stream) {
    (void)in_sizes; (void)n_in; (void)out_size; (void)d_ws; (void)ws_size;
    const float* f_feat = (const float*)d_in[0];
    const float* f_pts  = (const float*)d_in[1];
    const float* f_mask = (const float*)d_in[2];
    const float* f_time = (const float*)d_in[3];
    const float* enc_w1 = (const float*)d_in[4];
    const float* enc_b1 = (const float*)d_in[5];
    const float* enc_w2 = (const float*)d_in[6];
    const float* enc_b2 = (const float*)d_in[7];
    const float* four_w1 = (const float*)d_in[8];
    const float* four_w2 = (const float*)d_in[9];
    const float* time_w = (const float*)d_in[10];
    const float* l1w1 = (const float*)d_in[11];
    const float* l1b1 = (const float*)d_in[12];
    const float* l1w2 = (const float*)d_in[13];
    const float* l1b2 = (const float*)d_in[14];
    const float* l2w1 = (const float*)d_in[15];
    const float* l2b1 = (const float*)d_in[16];
    const float* l2w2 = (const float*)d_in[17];
    const float* l2b2 = (const float*)d_in[18];
    const float* qkv_w = (const float*)d_in[19];
    const float* qkv_b = (const float*)d_in[20];
    const float* out_w = (const float*)d_in[21];
    const float* out_b = (const float*)d_in[22];
    const float* ln1g = (const float*)d_in[23];
    const float* ln1b = (const float*)d_in[24];
    const float* ff1w = (const float*)d_in[25];
    const float* ff1b = (const float*)d_in[26];
    const float* ff2w = (const float*)d_in[27];
    const float* ff2b = (const float*)d_in[28];
    const float* gam  = (const float*)d_in[29];
    const float* ln2g = (const float*)d_in[30];
    const float* ln2b = (const float*)d_in[31];
    float* out = (float*)d_out;

    float *x, *skip, *lf1, *lf2, *dm, *big, *u, *r, *pqbias;
    int* idx;
    us *bigb, *xb, *attb, *lf1b, *pq, *h2b, *feat16, *wt;
    hipGetSymbolAddress((void**)&x,    HIP_SYMBOL(g_x));
    hipGetSymbolAddress((void**)&skip, HIP_SYMBOL(g_skip));
    hipGetSymbolAddress((void**)&lf1,  HIP_SYMBOL(g_lf1));
    hipGetSymbolAddress((void**)&lf2,  HIP_SYMBOL(g_lf2));
    hipGetSymbolAddress((void**)&dm,   HIP_SYMBOL(g_dm));
    hipGetSymbolAddress((void**)&big,  HIP_SYMBOL(g_big));
    hipGetSymbolAddress((void**)&u,    HIP_SYMBOL(g_u));
    hipGetSymbolAddress((void**)&r,    HIP_SYMBOL(g_r));
    hipGetSymbolAddress((void**)&pqbias, HIP_SYMBOL(g_pqbias));
    hipGetSymbolAddress((void**)&idx,  HIP_SYMBOL(g_idx));
    hipGetSymbolAddress((void**)&bigb, HIP_SYMBOL(g_bigb));
    hipGetSymbolAddress((void**)&xb,   HIP_SYMBOL(g_xb));
    hipGetSymbolAddress((void**)&attb, HIP_SYMBOL(g_attb));
    hipGetSymbolAddress((void**)&lf1b, HIP_SYMBOL(g_lf1b));
    hipGetSymbolAddress((void**)&pq,   HIP_SYMBOL(g_pq));
    hipGetSymbolAddress((void**)&h2b,  HIP_SYMBOL(g_h2b));
    hipGetSymbolAddress((void**)&feat16, HIP_SYMBOL(g_feat16));
    hipGetSymbolAddress((void**)&wt,   HIP_SYMBOL(g_wt));

    // ---- weight prep ----
    k_prep<<<dim3(8, 16, 1), 256, 0, stream>>>(enc_w2, wt + OFF_ENC2, 512, 512, 256, 0, 0);
    k_prep<<<dim3(8, 16, 1), 256, 0, stream>>>(l1w2, wt + OFF_W2A, 512, 512, 256, 0, 0);
    k_prep<<<dim3(8, 16, 1), 256, 0, stream>>>(l2w2, wt + OFF_W2B, 512, 512, 256, 0, 0);
    k_prepPQ<<<1024, 64, 0, stream>>>(l1w1, l1b1, wt + OFF_PQ1, pqbias, 13, 32);
    k_prepPQ<<<1024, 256, 0, stream>>>(l2w1, l2b1, wt + OFF_PQ2, pqbias + 1024, 256, 256);
    k_prep<<<dim3(24, 8, 8), 256, 0, stream>>>(qkv_w, wt + OFF_QKV, 256, 256, 768, 256 * 768, 768 * 256);
    k_prep<<<dim3(8, 8, 8), 256, 0, stream>>>(out_w, wt + OFF_OUT, 256, 256, 256, 256 * 256, 256 * 256);
    k_prep<<<dim3(16, 8, 8), 256, 0, stream>>>(ff1w, wt + OFF_FF1, 256, 256, 512, 256 * 512, 512 * 256);
    k_prep<<<dim3(8, 16, 8), 256, 0, stream>>>(ff2w, wt + OFF_FF2, 512, 512, 256, 512 * 256, 256 * 512);
    k_featpad<<<Tn * 32 / 256, 256, 0, stream>>>(f_feat, feat16);

    // ---- time embedding ----
    k_time<<<Bn, 256, 0, stream>>>(f_time, four_w1, four_w2, time_w, u);
    // ---- encoder ----
    k_enc1<<<Tn, 256, 0, stream>>>(f_feat, enc_w1, enc_b1, bigb);
    k_mg2<1, false><<<dim3(2, 128), 256, 0, stream>>>(bigb, wt + OFF_ENC2, enc_b2, x, 512, 256);
    // ---- knn pass 1 ----
    k_topk2<<<Bn, Nn, 0, stream>>>(f_pts, f_mask, idx);
    k_mg2<0, true><<<dim3(8, 128), 256, 0, stream>>>(feat16, wt + OFF_PQ1, pqbias, pq, 32, 1024);
    k_knng<<<Rn / 128, 512, 0, stream>>>(pq, idx, wt + OFF_W2A, l1b2, h2b);
    k_mean<<<Tn, 256, 0, stream>>>(h2b, lf1, lf1b);
    // ---- knn pass 2 ----
    k_shift<<<Tn * Dn / 256, 256, 0, stream>>>(lf1, f_mask, big);
    k_rnorm<<<Tn, 64, 0, stream>>>(big, r);
    k_dist<<<dim3(2, 2, Bn), 256, 0, stream>>>(big, r, dm);
    k_topkg<<<Bn, Nn, 0, stream>>>(dm, idx);
    k_mg2<0, true><<<dim3(8, 128), 256, 0, stream>>>(lf1b, wt + OFF_PQ2, pqbias + 1024, pq, 256, 1024);
    k_knng<<<Rn / 128, 512, 0, stream>>>(pq, idx, wt + OFF_W2B, l2b2, h2b);
    k_mean<<<Tn, 256, 0, stream>>>(h2b, lf2, nullptr);
    // ---- combine ----
    k_combine<<<Tn * 64 / 256, 256, 0, stream>>>(u, f_mask, lf2, x, skip, xb);
    // ---- transformer layers ----
    for (int l = 0; l < Ln; l++) {
        k_mg2<0, true><<<dim3(6, 128), 256, 0, stream>>>(
            xb, wt + OFF_QKV + (size_t)l * 768 * 256, qkv_b + l * 768, bigb, 256, 768);
        k_attn<<<Bn * 8, 128, 0, stream>>>(bigb, f_mask, attb);
        k_mg2<0, false><<<dim3(2, 128), 256, 0, stream>>>(
            attb, wt + OFF_OUT + (size_t)l * 256 * 256, out_b + l * 256, lf1, 256, 256);
        k_ln<false><<<Tn / 4, 256, 0, stream>>>(x, lf1, ln1g + l * Dn, ln1b + l * Dn, nullptr, f_mask, x, xb);
        k_mg2<1, true><<<dim3(4, 128), 256, 0, stream>>>(
            xb, wt + OFF_FF1 + (size_t)l * 512 * 256, ff1b + l * 512, bigb, 256, 512);
        k_mg2<0, false><<<dim3(2, 128), 256, 0, stream>>>(
            bigb, wt + OFF_FF2 + (size_t)l * 256 * 512, ff2b + l * 256, lf2, 512, 256);
        k_ln<true><<<Tn / 4, 256, 0, stream>>>(x, lf2, ln2g + l * Dn, ln2b + l * Dn, gam + l * Dn, f_mask, x, xb);
    }
    // ---- final residual ----
    k_out<<<Tn * 64 / 256, 256, 0, stream>>>(x, skip, out);
}

// Round 4
// 1667.403 us; speedup vs baseline: 9.7731x; 1.3980x over previous
//
#include <hip/hip_runtime.h>
#include <hip/hip_bf16.h>
#include <cmath>

#define DEV_INLINE __device__ __forceinline__

constexpr int Bn = 128;
constexpr int Nn = 128;
constexpr int Fn = 13;
constexpr int Dn = 256;
constexpr int Ln = 8;
constexpr int Kn = 10;
constexpr int FFn = 512;
constexpr int Tn = Bn * Nn;   // 16384
constexpr int Rn = Tn * Kn;   // 163840

typedef __attribute__((ext_vector_type(4))) float f32x4;
typedef __attribute__((ext_vector_type(8))) short bf16x8;
typedef unsigned short us;

// ---------------- static device workspace ----------------
__device__ float g_x[Tn * Dn];
__device__ float g_skip[Tn * Dn];
__device__ float g_lf1[Tn * Dn];
__device__ float g_lf2[Tn * Dn];
__device__ float g_dm[Tn * Nn];
__device__ float g_big[Tn * Dn];
__device__ float g_u[Bn * FFn];
__device__ float g_r[Tn];
__device__ float g_pqbias[2048];
__device__ int   g_idx[Rn];
__device__ us g_bigb[Tn * 768];
__device__ us g_xb[Tn * Dn];
__device__ us g_attb[Tn * Dn];
__device__ us g_lf1b[Tn * Dn];
__device__ us g_pq[Tn * 1024];
__device__ us g_h2b[Rn * Dn];
__device__ us g_feat16[Tn * 32];
constexpr int OFF_ENC2 = 0;
constexpr int OFF_W2A  = OFF_ENC2 + 256 * 512;
constexpr int OFF_W2B  = OFF_W2A + 256 * 512;
constexpr int OFF_PQ1  = OFF_W2B + 256 * 512;
constexpr int OFF_PQ2  = OFF_PQ1 + 1024 * 32;
constexpr int OFF_QKV  = OFF_PQ2 + 1024 * 256;
constexpr int OFF_OUT  = OFF_QKV + 8 * 768 * 256;
constexpr int OFF_FF1  = OFF_OUT + 8 * 256 * 256;
constexpr int OFF_FF2  = OFF_FF1 + 8 * 512 * 256;
constexpr int WT_TOTAL = OFF_FF2 + 8 * 256 * 512;
__device__ us g_wt[WT_TOTAL];

// fast gelu: 0.5x(1+tanh(u)) == x * sigmoid(2u) = x / (1 + exp(-2u))
DEV_INLINE float gelu_f(float x) {
    float x2 = x * x;
    float m = x * fmaf(x2, -0.07135537f, -1.59576912f); // -2u
    float t = __expf(m);
    return x * __builtin_amdgcn_rcpf(1.f + t);
}
DEV_INLINE us f2b(float x) {
    __hip_bfloat16 h = __float2bfloat16(x);
    return *(us*)&h;
}
DEV_INLINE float blo(unsigned u) { return __uint_as_float(u << 16); }
DEV_INLINE float bhi(unsigned u) { return __uint_as_float(u & 0xFFFF0000u); }
DEV_INLINE unsigned pk2(float a, float b) {
    float2 f; f.x = a; f.y = b;
    __hip_bfloat162 h = __float22bfloat162_rn(f);
    return *(unsigned*)&h;
}

#define GLOAD16(gp, lp)                                                            \
    __builtin_amdgcn_global_load_lds(                                              \
        (const __attribute__((address_space(1))) unsigned int*)(gp),               \
        (__attribute__((address_space(3))) unsigned int*)(lp), 16, 0, 0)

// ---------------- weight prep ----------------
__global__ __launch_bounds__(256) void k_prep(const float* __restrict__ src,
                                              us* __restrict__ dst,
                                              int Kreal, int Kpad, int Nd,
                                              long sstride, long dstride) {
    __shared__ float tile[32][33];
    int l = blockIdx.z;
    const float* s = src + (size_t)l * sstride;
    us* d = dst + (size_t)l * dstride;
    int tid = threadIdx.x;
    int cn = tid & 31, rk = tid >> 5;
    int kbase = blockIdx.y * 32, nbase = blockIdx.x * 32;
#pragma unroll
    for (int p = 0; p < 4; p++) {
        int k = kbase + p * 8 + rk;
        float v = (k < Kreal) ? s[(size_t)k * Nd + nbase + cn] : 0.f;
        tile[p * 8 + rk][cn] = v;
    }
    __syncthreads();
#pragma unroll
    for (int p = 0; p < 4; p++) {
        int nl = p * 8 + rk;
        d[(size_t)(nbase + nl) * Kpad + kbase + cn] = f2b(tile[cn][nl]);
    }
}

__global__ void k_prepPQ(const float* __restrict__ w1, const float* __restrict__ b1,
                         us* __restrict__ dst, float* __restrict__ bdst,
                         int Kreal, int Kpad) {
    int n = blockIdx.x;
    for (int k = threadIdx.x; k < Kpad; k += blockDim.x) {
        float v;
        if (n < 512) v = (k < Kreal) ? w1[(size_t)k * 512 + n] : 0.f;
        else {
            int m = n - 512;
            v = (k < Kreal) ? (w1[(size_t)(Kreal + k) * 512 + m] - w1[(size_t)k * 512 + m]) : 0.f;
        }
        dst[(size_t)n * Kpad + k] = f2b(v);
    }
    if (threadIdx.x == 0) bdst[n] = (n < 512) ? 0.f : b1[n - 512];
}

__global__ void k_featpad(const float* __restrict__ feat, us* __restrict__ fp) {
    int gid = blockIdx.x * 256 + threadIdx.x;
    int t = gid >> 5, c = gid & 31;
    fp[gid] = (c < Fn) ? f2b(feat[(size_t)t * Fn + c]) : (us)0;
}

// ---------------- MFMA GEMM: C = epi(A @ Bt^T + bias) ----------------
template <int EPI, bool OBF>
__global__ __launch_bounds__(256) void k_mg2(const us* __restrict__ A,
                                             const us* __restrict__ Bt,
                                             const float* __restrict__ bias,
                                             void* __restrict__ Cp,
                                             int Kd, int Nd) {
    __shared__ __align__(16) us As[128 * 32];
    __shared__ __align__(16) us Bs[128 * 32];
    int tid = threadIdx.x;
    int m0 = blockIdx.y << 7, n0 = blockIdx.x << 7;
    int wave = tid >> 6, lane = tid & 63;
    int wm = (wave & 1) << 6, wn = (wave >> 1) << 6;
    int lm = lane & 15, quad = lane >> 4;
    int r0 = (wave << 5) + (lane >> 2);
    int colu = (lane & 3) << 3;
    const us* pa0 = A + (size_t)(m0 + r0) * Kd + colu;
    const us* pa1 = A + (size_t)(m0 + r0 + 16) * Kd + colu;
    const us* pb0 = Bt + (size_t)(n0 + r0) * Kd + colu;
    const us* pb1 = Bt + (size_t)(n0 + r0 + 16) * Kd + colu;
    auto lAs = (__attribute__((address_space(3))) us*)As;
    auto lBs = (__attribute__((address_space(3))) us*)Bs;
    int lbase = wave << 10;
    f32x4 acc[4][4] = {};
    for (int k0 = 0; k0 < Kd; k0 += 32) {
        __syncthreads();
        GLOAD16(pa0 + k0, lAs + lbase);
        GLOAD16(pa1 + k0, lAs + lbase + 512);
        GLOAD16(pb0 + k0, lBs + lbase);
        GLOAD16(pb1 + k0, lBs + lbase + 512);
        __syncthreads();
        bf16x8 afr[4], bfr[4];
#pragma unroll
        for (int i = 0; i < 4; i++) {
            afr[i] = *(const bf16x8*)&As[(wm + i * 16 + lm) * 32 + (quad << 3)];
            bfr[i] = *(const bf16x8*)&Bs[(wn + i * 16 + lm) * 32 + (quad << 3)];
        }
#pragma unroll
        for (int mf = 0; mf < 4; mf++)
#pragma unroll
            for (int nf = 0; nf < 4; nf++)
                acc[mf][nf] = __builtin_amdgcn_mfma_f32_16x16x32_bf16(afr[mf], bfr[nf], acc[mf][nf], 0, 0, 0);
    }
    float bvs[4];
#pragma unroll
    for (int nf = 0; nf < 4; nf++) bvs[nf] = bias[n0 + wn + nf * 16 + lm];
#pragma unroll
    for (int mf = 0; mf < 4; mf++) {
#pragma unroll
        for (int r = 0; r < 4; r++) {
            size_t row = (size_t)(m0 + wm + mf * 16 + (quad << 2) + r);
#pragma unroll
            for (int nf = 0; nf < 4; nf++) {
                float v = acc[mf][nf][r] + bvs[nf];
                if (EPI == 1) v = gelu_f(v);
                size_t ci = row * Nd + n0 + wn + nf * 16 + lm;
                if constexpr (OBF) ((us*)Cp)[ci] = f2b(v);
                else ((float*)Cp)[ci] = v;
            }
        }
    }
}

// ---------------- fused KNN GEMM2 ----------------
__global__ __launch_bounds__(512) void k_knng(const us* __restrict__ pq,
                                              const int* __restrict__ idx,
                                              const us* __restrict__ Bt,
                                              const float* __restrict__ bias,
                                              us* __restrict__ h2b) {
    __shared__ __align__(16) us As[128 * 32];
    __shared__ __align__(16) us Bs[256 * 32];
    int tid = threadIdx.x;
    int m0 = blockIdx.x << 7;
    int wave = tid >> 6, lane = tid & 63;
    int wm = (wave & 1) << 6, wn = (wave >> 1) << 6;
    int lm = lane & 15, quad = lane >> 4;
    int arow = tid >> 2, acolu = (tid & 3) << 3;
    int r = m0 + arow;
    int tok = r / 10;
    int nb = idx[r];
    int prow = (tok & ~127) + nb;
    const us* Pp = pq + (size_t)prow * 1024 + acolu;
    const us* Qp = pq + (size_t)tok * 1024 + 512 + acolu;
    int r0 = (wave << 5) + (lane >> 2);
    int colu = (lane & 3) << 3;
    const us* pb0 = Bt + (size_t)r0 * 512 + colu;
    const us* pb1 = Bt + (size_t)(r0 + 16) * 512 + colu;
    auto lBs = (__attribute__((address_space(3))) us*)Bs;
    int lbase = wave << 10;
    f32x4 acc[4][4] = {};
    for (int k0 = 0; k0 < 512; k0 += 32) {
        uint4 pv = *(const uint4*)(Pp + k0);
        uint4 qv = *(const uint4*)(Qp + k0);
        uint4 hv;
        hv.x = pk2(gelu_f(blo(pv.x) + blo(qv.x)), gelu_f(bhi(pv.x) + bhi(qv.x)));
        hv.y = pk2(gelu_f(blo(pv.y) + blo(qv.y)), gelu_f(bhi(pv.y) + bhi(qv.y)));
        hv.z = pk2(gelu_f(blo(pv.z) + blo(qv.z)), gelu_f(bhi(pv.z) + bhi(qv.z)));
        hv.w = pk2(gelu_f(blo(pv.w) + blo(qv.w)), gelu_f(bhi(pv.w) + bhi(qv.w)));
        __syncthreads();
        GLOAD16(pb0 + k0, lBs + lbase);
        GLOAD16(pb1 + k0, lBs + lbase + 512);
        *(uint4*)&As[arow * 32 + acolu] = hv;
        __syncthreads();
        bf16x8 afr[4], bfr[4];
#pragma unroll
        for (int i = 0; i < 4; i++) {
            afr[i] = *(const bf16x8*)&As[(wm + i * 16 + lm) * 32 + (quad << 3)];
            bfr[i] = *(const bf16x8*)&Bs[(wn + i * 16 + lm) * 32 + (quad << 3)];
        }
#pragma unroll
        for (int mf = 0; mf < 4; mf++)
#pragma unroll
            for (int nf = 0; nf < 4; nf++)
                acc[mf][nf] = __builtin_amdgcn_mfma_f32_16x16x32_bf16(afr[mf], bfr[nf], acc[mf][nf], 0, 0, 0);
    }
    float bvs[4];
#pragma unroll
    for (int nf = 0; nf < 4; nf++) bvs[nf] = bias[wn + nf * 16 + lm];
#pragma unroll
    for (int mf = 0; mf < 4; mf++) {
#pragma unroll
        for (int rr = 0; rr < 4; rr++) {
            size_t row = (size_t)(m0 + wm + mf * 16 + (quad << 2) + rr);
#pragma unroll
            for (int nf = 0; nf < 4; nf++) {
                float v = gelu_f(acc[mf][nf][rr] + bvs[nf]);
                h2b[row * 256 + wn + nf * 16 + lm] = f2b(v);
            }
        }
    }
}

__global__ __launch_bounds__(256) void k_mean(const us* __restrict__ h2b,
                                              float* __restrict__ lf, us* __restrict__ lfb) {
    int t = blockIdx.x, c = threadIdx.x;
    const us* p = h2b + (size_t)t * Kn * 256 + c;
    float s = 0.f;
#pragma unroll
    for (int k = 0; k < Kn; k++) s += blo((unsigned)p[k * 256]);
    s *= 0.1f;
    lf[(size_t)t * 256 + c] = s;
    if (lfb) lfb[(size_t)t * 256 + c] = f2b(s);
}

// ---------------- time / fourier MLP ----------------
__global__ __launch_bounds__(256) void k_time(const float* __restrict__ tin,
                                              const float* __restrict__ w1,
                                              const float* __restrict__ w2,
                                              const float* __restrict__ tw,
                                              float* __restrict__ u) {
    __shared__ float e[256], e1[512], t2[256];
    int b = blockIdx.x, tid = threadIdx.x;
    float tv = tin[b];
    if (tid < 128) {
        const float emb = 0.07252236513366287f;
        float fr = expf(-emb * (float)tid);
        float ang = tv * fr * 1000.f;
        e[tid] = sinf(ang);
        e[tid + 128] = cosf(ang);
    }
    __syncthreads();
    for (int j = tid; j < 512; j += 256) {
        float s = 0.f;
        for (int i = 0; i < 256; i++) s += e[i] * w1[(size_t)i * 512 + j];
        e1[j] = s / (1.f + expf(-s));
    }
    __syncthreads();
    {
        float s = 0.f;
        for (int i = 0; i < 512; i++) s += e1[i] * w2[(size_t)i * 256 + tid];
        t2[tid] = s / (1.f + expf(-s));
    }
    __syncthreads();
    for (int j = tid; j < 512; j += 256) {
        float s = 0.f;
        for (int i = 0; i < 256; i++) s += t2[i] * tw[(size_t)i * 512 + j];
        u[(size_t)b * 512 + j] = s;
    }
}

// ---------------- encoder stage 1 ----------------
__global__ __launch_bounds__(256) void k_enc1(const float* __restrict__ feat,
                                              const float* __restrict__ w1,
                                              const float* __restrict__ b1,
                                              us* __restrict__ Hb) {
    __shared__ float f[16];
    int t = blockIdx.x, tid = threadIdx.x;
    if (tid < Fn) f[tid] = feat[(size_t)t * Fn + tid];
    __syncthreads();
    for (int j = tid; j < FFn; j += 256) {
        float s = b1[j];
#pragma unroll
        for (int i = 0; i < Fn; i++) s += f[i] * w1[(size_t)i * FFn + j];
        Hb[(size_t)t * FFn + j] = f2b(gelu_f(s));
    }
}

// ---------------- knn top-k on 2-d points ----------------
__global__ __launch_bounds__(128) void k_topk2(const float* __restrict__ pts,
                                               const float* __restrict__ mask,
                                               int* __restrict__ idx) {
    int b = blockIdx.x, n = threadIdx.x;
    __shared__ float px[Nn], py[Nn], rr[Nn];
    float shift = 999.f * (1.f - mask[b * Nn + n]);
    float x = pts[(size_t)(b * Nn + n) * 2 + 0] + shift;
    float y = pts[(size_t)(b * Nn + n) * 2 + 1] + shift;
    px[n] = x; py[n] = y; rr[n] = x * x + y * y;
    __syncthreads();
    float rn = rr[n];
    float bd[Kn + 1]; int bi[Kn + 1];
#pragma unroll
    for (int j = 0; j <= Kn; j++) { bd[j] = 3.4e38f; bi[j] = -1; }
    for (int m = 0; m < Nn; m++) {
        float d = rn - 2.f * (x * px[m] + y * py[m]) + rr[m];
        if (d < bd[Kn]) {
            int j = Kn;
            while (j > 0 && d < bd[j - 1]) { bd[j] = bd[j - 1]; bi[j] = bi[j - 1]; j--; }
            bd[j] = d; bi[j] = m;
        }
    }
    for (int j = 1; j <= Kn; j++) idx[(size_t)(b * Nn + n) * Kn + j - 1] = bi[j];
}

// ---------------- fused shift + rownorm ----------------
__global__ __launch_bounds__(64) void k_shiftnorm(const float* __restrict__ lf,
                                                  const float* __restrict__ mask,
                                                  float* __restrict__ o,
                                                  float* __restrict__ r) {
    int t = blockIdx.x, lane = threadIdx.x;
    float sh = 999.f * (1.f - mask[t]);
    float4 v = *(const float4*)&lf[(size_t)t * 256 + lane * 4];
    v.x += sh; v.y += sh; v.z += sh; v.w += sh;
    *(float4*)&o[(size_t)t * 256 + lane * 4] = v;
    float s = v.x * v.x + v.y * v.y + v.z * v.z + v.w * v.w;
#pragma unroll
    for (int off = 32; off; off >>= 1) s += __shfl_xor(s, off, 64);
    if (lane == 0) r[t] = s;
}

__global__ __launch_bounds__(256) void k_dist(const float* __restrict__ fe,
                                              const float* __restrict__ r,
                                              float* __restrict__ Dm) {
    int b = blockIdx.z;
    int m0 = blockIdx.x * 64, n0 = blockIdx.y * 64;
    const float* A = fe + (size_t)b * Nn * Dn;
    __shared__ float As[16][68];
    __shared__ float Bs[16][68];
    int tid = threadIdx.x;
    int tx = tid & 15, ty = tid >> 4;
    int ar = tid >> 2, ac = (tid & 3) << 2;
    float acc[4][4] = {};
    for (int k0 = 0; k0 < Dn; k0 += 16) {
        float4 av = *(const float4*)&A[(size_t)(n0 + ar) * Dn + k0 + ac];
        float4 bv = *(const float4*)&A[(size_t)(m0 + ar) * Dn + k0 + ac];
        __syncthreads();
        As[ac + 0][ar] = av.x; As[ac + 1][ar] = av.y; As[ac + 2][ar] = av.z; As[ac + 3][ar] = av.w;
        Bs[ac + 0][ar] = bv.x; Bs[ac + 1][ar] = bv.y; Bs[ac + 2][ar] = bv.z; Bs[ac + 3][ar] = bv.w;
        __syncthreads();
#pragma unroll
        for (int kk = 0; kk < 16; kk++) {
            float4 a = *(const float4*)&As[kk][ty << 2];
            float4 b2 = *(const float4*)&Bs[kk][tx << 2];
            acc[0][0] += a.x * b2.x; acc[0][1] += a.x * b2.y; acc[0][2] += a.x * b2.z; acc[0][3] += a.x * b2.w;
            acc[1][0] += a.y * b2.x; acc[1][1] += a.y * b2.y; acc[1][2] += a.y * b2.z; acc[1][3] += a.y * b2.w;
            acc[2][0] += a.z * b2.x; acc[2][1] += a.z * b2.y; acc[2][2] += a.z * b2.z; acc[2][3] += a.z * b2.w;
            acc[3][0] += a.w * b2.x; acc[3][1] += a.w * b2.y; acc[3][2] += a.w * b2.z; acc[3][3] += a.w * b2.w;
        }
    }
    float4 rm = *(const float4*)&r[b * Nn + m0 + (tx << 2)];
#pragma unroll
    for (int i = 0; i < 4; i++) {
        int n = n0 + (ty << 2) + i;
        float rn = r[b * Nn + n];
        float4 v;
        v.x = rn - 2.f * acc[i][0] + rm.x;
        v.y = rn - 2.f * acc[i][1] + rm.y;
        v.z = rn - 2.f * acc[i][2] + rm.z;
        v.w = rn - 2.f * acc[i][3] + rm.w;
        *(float4*)&Dm[(size_t)b * Nn * Nn + (size_t)n * Nn + m0 + (tx << 2)] = v;
    }
}

__global__ __launch_bounds__(128) void k_topkg(const float* __restrict__ Dm, int* __restrict__ idx) {
    int b = blockIdx.x, n = threadIdx.x;
    const float* row = Dm + (size_t)b * Nn * Nn + (size_t)n * Nn;
    float bd[Kn + 1]; int bi[Kn + 1];
#pragma unroll
    for (int j = 0; j <= Kn; j++) { bd[j] = 3.4e38f; bi[j] = -1; }
    for (int m = 0; m < Nn; m++) {
        float d = row[m];
        if (d < bd[Kn]) {
            int j = Kn;
            while (j > 0 && d < bd[j - 1]) { bd[j] = bd[j - 1]; bi[j] = bi[j - 1]; j--; }
            bd[j] = d; bi[j] = m;
        }
    }
    for (int j = 1; j <= Kn; j++) idx[(size_t)(b * Nn + n) * Kn + j - 1] = bi[j];
}

// ---------------- combine ----------------
__global__ void k_combine(const float* __restrict__ u, const float* __restrict__ mask,
                          const float* __restrict__ lf2, float* __restrict__ x,
                          float* __restrict__ skip, us* __restrict__ xb) {
    int gid = blockIdx.x * 256 + threadIdx.x;
    int t = gid >> 6;
    int c = (gid & 63) << 2;
    int b = t >> 7;
    float m = mask[t];
    float4 xv = *(const float4*)&x[(size_t)t * Dn + c];
    float4 lv = *(const float4*)&lf2[(size_t)t * Dn + c];
    float4 sc = *(const float4*)&u[(size_t)b * 512 + c];
    float4 sh = *(const float4*)&u[(size_t)b * 512 + 256 + c];
    float4 v;
    v.x = xv.x * (1.f + m * sc.x) + m * sh.x + lv.x;
    v.y = xv.y * (1.f + m * sc.y) + m * sh.y + lv.y;
    v.z = xv.z * (1.f + m * sc.z) + m * sh.z + lv.z;
    v.w = xv.w * (1.f + m * sc.w) + m * sh.w + lv.w;
    *(float4*)&x[(size_t)t * Dn + c] = v;
    *(float4*)&skip[(size_t)t * Dn + c] = v;
    uint2 p; p.x = pk2(v.x, v.y); p.y = pk2(v.z, v.w);
    *(uint2*)&xb[(size_t)t * Dn + c] = p;
}

// ---------------- MFMA attention: block per (b,h), 4 waves ----------------
__global__ __launch_bounds__(256) void k_attn(const us* __restrict__ qkv,
                                              const float* __restrict__ mask,
                                              us* __restrict__ outp) {
    __shared__ __align__(16) us Qs[128 * 40];
    __shared__ __align__(16) us Ks[128 * 40];
    __shared__ __align__(16) us Vt[32 * 136];
    __shared__ __align__(16) us Ps[128 * 136];
    __shared__ float msk[128];
    int bh = blockIdx.x;
    int b = bh >> 3, h = bh & 7;
    int tid = threadIdx.x;
    int wave = tid >> 6, lane = tid & 63;
    int lm = lane & 15, quad = lane >> 4;
    int wm = wave << 5;
    // staging: thread -> (row = tid/2, 16 cols at off)
    {
        int row = tid >> 1, off = (tid & 1) << 4;
        const us* rp = qkv + (size_t)(b * 128 + row) * 768 + h * 32 + off;
        *(uint4*)&Qs[row * 40 + off] = *(const uint4*)(rp);
        *(uint4*)&Qs[row * 40 + off + 8] = *(const uint4*)(rp + 8);
        *(uint4*)&Ks[row * 40 + off] = *(const uint4*)(rp + 256);
        *(uint4*)&Ks[row * 40 + off + 8] = *(const uint4*)(rp + 264);
        union { uint4 u[2]; us s[16]; } tv;
        tv.u[0] = *(const uint4*)(rp + 512);
        tv.u[1] = *(const uint4*)(rp + 520);
#pragma unroll
        for (int j = 0; j < 16; j++) Vt[(off + j) * 136 + row] = tv.s[j];
        if (tid < 128) msk[tid] = mask[b * 128 + tid];
    }
    __syncthreads();
    // S = Q @ K^T for rows [wm, wm+32)
    f32x4 acc[2][8] = {};
    {
        bf16x8 aq[2];
#pragma unroll
        for (int mf = 0; mf < 2; mf++)
            aq[mf] = *(const bf16x8*)&Qs[(wm + mf * 16 + lm) * 40 + (quad << 3)];
#pragma unroll
        for (int nf = 0; nf < 8; nf++) {
            bf16x8 bk = *(const bf16x8*)&Ks[(nf * 16 + lm) * 40 + (quad << 3)];
            acc[0][nf] = __builtin_amdgcn_mfma_f32_16x16x32_bf16(aq[0], bk, acc[0][nf], 0, 0, 0);
            acc[1][nf] = __builtin_amdgcn_mfma_f32_16x16x32_bf16(aq[1], bk, acc[1][nf], 0, 0, 0);
        }
    }
    // masked softmax over cols; write normalized P (bf16) to LDS
    {
        const float sc = 0.17677669529663687f;
        float mkc[8];
#pragma unroll
        for (int nf = 0; nf < 8; nf++) mkc[nf] = msk[nf * 16 + lm];
#pragma unroll
        for (int mf = 0; mf < 2; mf++) {
#pragma unroll
            for (int nf = 0; nf < 8; nf++)
#pragma unroll
                for (int r = 0; r < 4; r++) {
                    float s = acc[mf][nf][r];
                    acc[mf][nf][r] = mkc[nf] > 0.f ? s * sc : -1.0e9f;
                }
#pragma unroll
            for (int r = 0; r < 4; r++) {
                float m = acc[mf][0][r];
#pragma unroll
                for (int nf = 1; nf < 8; nf++) m = fmaxf(m, acc[mf][nf][r]);
                m = fmaxf(m, __shfl_xor(m, 1, 64));
                m = fmaxf(m, __shfl_xor(m, 2, 64));
                m = fmaxf(m, __shfl_xor(m, 4, 64));
                m = fmaxf(m, __shfl_xor(m, 8, 64));
                float s = 0.f;
#pragma unroll
                for (int nf = 0; nf < 8; nf++) {
                    float p = __expf(acc[mf][nf][r] - m);
                    acc[mf][nf][r] = p;
                    s += p;
                }
                s += __shfl_xor(s, 1, 64);
                s += __shfl_xor(s, 2, 64);
                s += __shfl_xor(s, 4, 64);
                s += __shfl_xor(s, 8, 64);
                float linv = __builtin_amdgcn_rcpf(s);
                int prow = wm + mf * 16 + (quad << 2) + r;
#pragma unroll
                for (int nf = 0; nf < 8; nf++)
                    Ps[prow * 136 + nf * 16 + lm] = f2b(acc[mf][nf][r] * linv);
            }
        }
    }
    __syncthreads();
    // O = P @ V for rows [wm, wm+32), dims 0..32
    f32x4 oacc[2][2] = {};
    for (int kt = 0; kt < 4; kt++) {
        bf16x8 ap[2], bv[2];
#pragma unroll
        for (int mf = 0; mf < 2; mf++)
            ap[mf] = *(const bf16x8*)&Ps[(wm + mf * 16 + lm) * 136 + kt * 32 + (quad << 3)];
#pragma unroll
        for (int nf = 0; nf < 2; nf++)
            bv[nf] = *(const bf16x8*)&Vt[(nf * 16 + lm) * 136 + kt * 32 + (quad << 3)];
#pragma unroll
        for (int mf = 0; mf < 2; mf++)
#pragma unroll
            for (int nf = 0; nf < 2; nf++)
                oacc[mf][nf] = __builtin_amdgcn_mfma_f32_16x16x32_bf16(ap[mf], bv[nf], oacc[mf][nf], 0, 0, 0);
    }
#pragma unroll
    for (int mf = 0; mf < 2; mf++)
#pragma unroll
        for (int r = 0; r < 4; r++) {
            int row = wm + mf * 16 + (quad << 2) + r;
#pragma unroll
            for (int nf = 0; nf < 2; nf++)
                outp[(size_t)(b * 128 + row) * 256 + h * 32 + nf * 16 + lm] = f2b(oacc[mf][nf][r]);
        }
}

// ---------------- layernorm ----------------
template <bool PM>
__global__ __launch_bounds__(256) void k_ln(const float* __restrict__ res,
                                            const float* __restrict__ del,
                                            const float* __restrict__ g,
                                            const float* __restrict__ beta,
                                            const float* __restrict__ gamma,
                                            const float* __restrict__ mask,
                                            float* __restrict__ outp,
                                            us* __restrict__ outb) {
    int wid = threadIdx.x >> 6, lane = threadIdx.x & 63;
    int t = blockIdx.x * 4 + wid;
    int c = lane << 2;
    float4 rv = *(const float4*)&res[(size_t)t * Dn + c];
    float4 dv = *(const float4*)&del[(size_t)t * Dn + c];
    float x0, x1, x2, x3;
    if (PM) {
        float m = mask[t];
        x0 = rv.x + dv.x * gamma[c + 0] * m;
        x1 = rv.y + dv.y * gamma[c + 1] * m;
        x2 = rv.z + dv.z * gamma[c + 2] * m;
        x3 = rv.w + dv.w * gamma[c + 3] * m;
    } else {
        x0 = rv.x + dv.x; x1 = rv.y + dv.y; x2 = rv.z + dv.z; x3 = rv.w + dv.w;
    }
    float s = x0 + x1 + x2 + x3;
#pragma unroll
    for (int off = 1; off < 64; off <<= 1) s += __shfl_xor(s, off, 64);
    float mean = s * (1.f / 256.f);
    float e0 = x0 - mean, e1 = x1 - mean, e2 = x2 - mean, e3 = x3 - mean;
    float qd = e0 * e0 + e1 * e1 + e2 * e2 + e3 * e3;
#pragma unroll
    for (int off = 1; off < 64; off <<= 1) qd += __shfl_xor(qd, off, 64);
    float rs = rsqrtf(qd * (1.f / 256.f) + 1e-5f);
    float4 ov;
    ov.x = e0 * rs * g[c + 0] + beta[c + 0];
    ov.y = e1 * rs * g[c + 1] + beta[c + 1];
    ov.z = e2 * rs * g[c + 2] + beta[c + 2];
    ov.w = e3 * rs * g[c + 3] + beta[c + 3];
    *(float4*)&outp[(size_t)t * Dn + c] = ov;
    uint2 p; p.x = pk2(ov.x, ov.y); p.y = pk2(ov.z, ov.w);
    *(uint2*)&outb[(size_t)t * Dn + c] = p;
}

__global__ void k_out(const float* __restrict__ x, const float* __restrict__ skip,
                      float* __restrict__ o) {
    int gid = blockIdx.x * 256 + threadIdx.x;
    float4 a = *(const float4*)&x[(size_t)gid * 4];
    float4 b = *(const float4*)&skip[(size_t)gid * 4];
    float4 v; v.x = a.x + b.x; v.y = a.y + b.y; v.z = a.z + b.z; v.w = a.w + b.w;
    *(float4*)&o[(size_t)gid * 4] = v;
}

extern "C" void kernel_launch(void* const* d_in, const int* in_sizes, int n_in,
                              void* d_out, int out_size, void* d_ws, size_t ws_size,
                              hipStream_t stream) {
    (void)in_sizes; (void)n_in; (void)out_size; (void)d_ws; (void)ws_size;
    const float* f_feat = (const float*)d_in[0];
    const float* f_pts  = (const float*)d_in[1];
    const float* f_mask = (const float*)d_in[2];
    const float* f_time = (const float*)d_in[3];
    const float* enc_w1 = (const float*)d_in[4];
    const float* enc_b1 = (const float*)d_in[5];
    const float* enc_w2 = (const float*)d_in[6];
    const float* enc_b2 = (const float*)d_in[7];
    const float* four_w1 = (const float*)d_in[8];
    const float* four_w2 = (const float*)d_in[9];
    const float* time_w = (const float*)d_in[10];
    const float* l1w1 = (const float*)d_in[11];
    const float* l1b1 = (const float*)d_in[12];
    const float* l1w2 = (const float*)d_in[13];
    const float* l1b2 = (const float*)d_in[14];
    const float* l2w1 = (const float*)d_in[15];
    const float* l2b1 = (const float*)d_in[16];
    const float* l2w2 = (const float*)d_in[17];
    const float* l2b2 = (const float*)d_in[18];
    const float* qkv_w = (const float*)d_in[19];
    const float* qkv_b = (const float*)d_in[20];
    const float* out_w = (const float*)d_in[21];
    const float* out_b = (const float*)d_in[22];
    const float* ln1g = (const float*)d_in[23];
    const float* ln1b = (const float*)d_in[24];
    const float* ff1w = (const float*)d_in[25];
    const float* ff1b = (const float*)d_in[26];
    const float* ff2w = (const float*)d_in[27];
    const float* ff2b = (const float*)d_in[28];
    const float* gam  = (const float*)d_in[29];
    const float* ln2g = (const float*)d_in[30];
    const float* ln2b = (const float*)d_in[31];
    float* out = (float*)d_out;

    float *x, *skip, *lf1, *lf2, *dm, *big, *u, *r, *pqbias;
    int* idx;
    us *bigb, *xb, *attb, *lf1b, *pq, *h2b, *feat16, *wt;
    hipGetSymbolAddress((void**)&x,    HIP_SYMBOL(g_x));
    hipGetSymbolAddress((void**)&skip, HIP_SYMBOL(g_skip));
    hipGetSymbolAddress((void**)&lf1,  HIP_SYMBOL(g_lf1));
    hipGetSymbolAddress((void**)&lf2,  HIP_SYMBOL(g_lf2));
    hipGetSymbolAddress((void**)&dm,   HIP_SYMBOL(g_dm));
    hipGetSymbolAddress((void**)&big,  HIP_SYMBOL(g_big));
    hipGetSymbolAddress((void**)&u,    HIP_SYMBOL(g_u));
    hipGetSymbolAddress((void**)&r,    HIP_SYMBOL(g_r));
    hipGetSymbolAddress((void**)&pqbias, HIP_SYMBOL(g_pqbias));
    hipGetSymbolAddress((void**)&idx,  HIP_SYMBOL(g_idx));
    hipGetSymbolAddress((void**)&bigb, HIP_SYMBOL(g_bigb));
    hipGetSymbolAddress((void**)&xb,   HIP_SYMBOL(g_xb));
    hipGetSymbolAddress((void**)&attb, HIP_SYMBOL(g_attb));
    hipGetSymbolAddress((void**)&lf1b, HIP_SYMBOL(g_lf1b));
    hipGetSymbolAddress((void**)&pq,   HIP_SYMBOL(g_pq));
    hipGetSymbolAddress((void**)&h2b,  HIP_SYMBOL(g_h2b));
    hipGetSymbolAddress((void**)&feat16, HIP_SYMBOL(g_feat16));
    hipGetSymbolAddress((void**)&wt,   HIP_SYMBOL(g_wt));

    // ---- weight prep ----
    k_prep<<<dim3(8, 16, 1), 256, 0, stream>>>(enc_w2, wt + OFF_ENC2, 512, 512, 256, 0, 0);
    k_prep<<<dim3(8, 16, 1), 256, 0, stream>>>(l1w2, wt + OFF_W2A, 512, 512, 256, 0, 0);
    k_prep<<<dim3(8, 16, 1), 256, 0, stream>>>(l2w2, wt + OFF_W2B, 512, 512, 256, 0, 0);
    k_prepPQ<<<1024, 64, 0, stream>>>(l1w1, l1b1, wt + OFF_PQ1, pqbias, 13, 32);
    k_prepPQ<<<1024, 256, 0, stream>>>(l2w1, l2b1, wt + OFF_PQ2, pqbias + 1024, 256, 256);
    k_prep<<<dim3(24, 8, 8), 256, 0, stream>>>(qkv_w, wt + OFF_QKV, 256, 256, 768, 256 * 768, 768 * 256);
    k_prep<<<dim3(8, 8, 8), 256, 0, stream>>>(out_w, wt + OFF_OUT, 256, 256, 256, 256 * 256, 256 * 256);
    k_prep<<<dim3(16, 8, 8), 256, 0, stream>>>(ff1w, wt + OFF_FF1, 256, 256, 512, 256 * 512, 512 * 256);
    k_prep<<<dim3(8, 16, 8), 256, 0, stream>>>(ff2w, wt + OFF_FF2, 512, 512, 256, 512 * 256, 256 * 512);
    k_featpad<<<Tn * 32 / 256, 256, 0, stream>>>(f_feat, feat16);

    // ---- time embedding ----
    k_time<<<Bn, 256, 0, stream>>>(f_time, four_w1, four_w2, time_w, u);
    // ---- encoder ----
    k_enc1<<<Tn, 256, 0, stream>>>(f_feat, enc_w1, enc_b1, bigb);
    k_mg2<1, false><<<dim3(2, 128), 256, 0, stream>>>(bigb, wt + OFF_ENC2, enc_b2, x, 512, 256);
    // ---- knn pass 1 ----
    k_topk2<<<Bn, Nn, 0, stream>>>(f_pts, f_mask, idx);
    k_mg2<0, true><<<dim3(8, 128), 256, 0, stream>>>(feat16, wt + OFF_PQ1, pqbias, pq, 32, 1024);
    k_knng<<<Rn / 128, 512, 0, stream>>>(pq, idx, wt + OFF_W2A, l1b2, h2b);
    k_mean<<<Tn, 256, 0, stream>>>(h2b, lf1, lf1b);
    // ---- knn pass 2 ----
    k_shiftnorm<<<Tn, 64, 0, stream>>>(lf1, f_mask, big, r);
    k_dist<<<dim3(2, 2, Bn), 256, 0, stream>>>(big, r, dm);
    k_topkg<<<Bn, Nn, 0, stream>>>(dm, idx);
    k_mg2<0, true><<<dim3(8, 128), 256, 0, stream>>>(lf1b, wt + OFF_PQ2, pqbias + 1024, pq, 256, 1024);
    k_knng<<<Rn / 128, 512, 0, stream>>>(pq, idx, wt + OFF_W2B, l2b2, h2b);
    k_mean<<<Tn, 256, 0, stream>>>(h2b, lf2, nullptr);
    // ---- combine ----
    k_combine<<<Tn * 64 / 256, 256, 0, stream>>>(u, f_mask, lf2, x, skip, xb);
    // ---- transformer layers ----
    for (int l = 0; l < Ln; l++) {
        k_mg2<0, true><<<dim3(6, 128), 256, 0, stream>>>(
            xb, wt + OFF_QKV + (size_t)l * 768 * 256, qkv_b + l * 768, bigb, 256, 768);
        k_attn<<<Bn * 8, 256, 0, stream>>>(bigb, f_mask, attb);
        k_mg2<0, false><<<dim3(2, 128), 256, 0, stream>>>(
            attb, wt + OFF_OUT + (size_t)l * 256 * 256, out_b + l * 256, lf1, 256, 256);
        k_ln<false><<<Tn / 4, 256, 0, stream>>>(x, lf1, ln1g + l * Dn, ln1b + l * Dn, nullptr, f_mask, x, xb);
        k_mg2<1, true><<<dim3(4, 128), 256, 0, stream>>>(
            xb, wt + OFF_FF1 + (size_t)l * 512 * 256, ff1b + l * 512, bigb, 256, 512);
        k_mg2<0, false><<<dim3(2, 128), 256, 0, stream>>>(
            bigb, wt + OFF_FF2 + (size_t)l * 256 * 512, ff2b + l * 256, lf2, 512, 256);
        k_ln<true><<<Tn / 4, 256, 0, stream>>>(x, lf2, ln2g + l * Dn, ln2b + l * Dn, gam + l * Dn, f_mask, x, xb);
    }
    // ---- final residual ----
    k_out<<<Tn * 64 / 256, 256, 0, stream>>>(x, skip, out);
}

// Round 5
// 1488.316 us; speedup vs baseline: 10.9490x; 1.1203x over previous
//
#include <hip/hip_runtime.h>
#include <hip/hip_bf16.h>
#include <cmath>

#define DEV_INLINE __device__ __forceinline__

constexpr int Bn = 128;
constexpr int Nn = 128;
constexpr int Fn = 13;
constexpr int Dn = 256;
constexpr int Ln = 8;
constexpr int Kn = 10;
constexpr int FFn = 512;
constexpr int Tn = Bn * Nn;   // 16384
constexpr int Rn = Tn * Kn;   // 163840

typedef __attribute__((ext_vector_type(4))) float f32x4;
typedef __attribute__((ext_vector_type(8))) short bf16x8;
typedef unsigned short us;

// ---------------- static device workspace ----------------
__device__ float g_x[Tn * Dn];
__device__ float g_skip[Tn * Dn];
__device__ float g_lf2[Tn * Dn];
__device__ float g_dm[Tn * Nn];
__device__ float g_big[Tn * Dn];
__device__ float g_u[Bn * FFn];
__device__ float g_r[Tn];
__device__ float g_pqbias[2048];
__device__ int   g_idx[Rn];
__device__ us g_bigb[Tn * 768];
__device__ us g_xb[Tn * Dn];
__device__ us g_attb[Tn * Dn];
__device__ us g_lf1b[Tn * Dn];
__device__ us g_pq[Tn * 1024];
__device__ us g_h2b[Rn * Dn];
__device__ us g_feat16[Tn * 32];
constexpr int OFF_ENC1 = 0;
constexpr int OFF_ENC2 = OFF_ENC1 + 512 * 32;
constexpr int OFF_W2A  = OFF_ENC2 + 256 * 512;
constexpr int OFF_W2B  = OFF_W2A + 256 * 512;
constexpr int OFF_PQ1  = OFF_W2B + 256 * 512;
constexpr int OFF_PQ2  = OFF_PQ1 + 1024 * 32;
constexpr int OFF_QKV  = OFF_PQ2 + 1024 * 256;
constexpr int OFF_OUT  = OFF_QKV + 8 * 768 * 256;
constexpr int OFF_FF1  = OFF_OUT + 8 * 256 * 256;
constexpr int OFF_FF2  = OFF_FF1 + 8 * 512 * 256;
constexpr int WT_TOTAL = OFF_FF2 + 8 * 256 * 512;
__device__ us g_wt[WT_TOTAL];

// fast gelu: 0.5x(1+tanh(u)) == x / (1 + exp(-2u))
DEV_INLINE float gelu_f(float x) {
    float x2 = x * x;
    float m = x * fmaf(x2, -0.07135537f, -1.59576912f); // -2u
    float t = __expf(m);
    return x * __builtin_amdgcn_rcpf(1.f + t);
}
DEV_INLINE us f2b(float x) {
    __hip_bfloat16 h = __float2bfloat16(x);
    return *(us*)&h;
}
DEV_INLINE float blo(unsigned u) { return __uint_as_float(u << 16); }
DEV_INLINE float bhi(unsigned u) { return __uint_as_float(u & 0xFFFF0000u); }
DEV_INLINE unsigned pk2(float a, float b) {
    float2 f; f.x = a; f.y = b;
    __hip_bfloat162 h = __float22bfloat162_rn(f);
    return *(unsigned*)&h;
}

#define GLOAD16(gp, lp)                                                            \
    __builtin_amdgcn_global_load_lds(                                              \
        (const __attribute__((address_space(1))) unsigned int*)(gp),               \
        (__attribute__((address_space(3))) unsigned int*)(lp), 16, 0, 0)

// ---------------- weight prep ----------------
__global__ __launch_bounds__(256) void k_prep(const float* __restrict__ src,
                                              us* __restrict__ dst,
                                              int Kreal, int Kpad, int Nd,
                                              long sstride, long dstride) {
    __shared__ float tile[32][33];
    int l = blockIdx.z;
    const float* s = src + (size_t)l * sstride;
    us* d = dst + (size_t)l * dstride;
    int tid = threadIdx.x;
    int cn = tid & 31, rk = tid >> 5;
    int kbase = blockIdx.y * 32, nbase = blockIdx.x * 32;
#pragma unroll
    for (int p = 0; p < 4; p++) {
        int k = kbase + p * 8 + rk;
        float v = (k < Kreal) ? s[(size_t)k * Nd + nbase + cn] : 0.f;
        tile[p * 8 + rk][cn] = v;
    }
    __syncthreads();
#pragma unroll
    for (int p = 0; p < 4; p++) {
        int nl = p * 8 + rk;
        d[(size_t)(nbase + nl) * Kpad + kbase + cn] = f2b(tile[cn][nl]);
    }
}

__global__ void k_prepPQ(const float* __restrict__ w1, const float* __restrict__ b1,
                         us* __restrict__ dst, float* __restrict__ bdst,
                         int Kreal, int Kpad) {
    int n = blockIdx.x;
    for (int k = threadIdx.x; k < Kpad; k += blockDim.x) {
        float v;
        if (n < 512) v = (k < Kreal) ? w1[(size_t)k * 512 + n] : 0.f;
        else {
            int m = n - 512;
            v = (k < Kreal) ? (w1[(size_t)(Kreal + k) * 512 + m] - w1[(size_t)k * 512 + m]) : 0.f;
        }
        dst[(size_t)n * Kpad + k] = f2b(v);
    }
    if (threadIdx.x == 0) bdst[n] = (n < 512) ? 0.f : b1[n - 512];
}

__global__ void k_featpad(const float* __restrict__ feat, us* __restrict__ fp) {
    int gid = blockIdx.x * 256 + threadIdx.x;
    int t = gid >> 5, c = gid & 31;
    fp[gid] = (c < Fn) ? f2b(feat[(size_t)t * Fn + c]) : (us)0;
}

// ---------------- MFMA GEMM: C = epi(A @ Bt^T + bias), 128x128 tile ----------------
template <int EPI, bool OBF>
__global__ __launch_bounds__(256) void k_mg2(const us* __restrict__ A,
                                             const us* __restrict__ Bt,
                                             const float* __restrict__ bias,
                                             void* __restrict__ Cp,
                                             int Kd, int Nd) {
    __shared__ __align__(16) us As[128 * 32];
    __shared__ __align__(16) us Bs[128 * 32];
    int tid = threadIdx.x;
    int m0 = blockIdx.y << 7, n0 = blockIdx.x << 7;
    int wave = tid >> 6, lane = tid & 63;
    int wm = (wave & 1) << 6, wn = (wave >> 1) << 6;
    int lm = lane & 15, quad = lane >> 4;
    int r0 = (wave << 5) + (lane >> 2);
    int colu = (lane & 3) << 3;
    const us* pa0 = A + (size_t)(m0 + r0) * Kd + colu;
    const us* pa1 = A + (size_t)(m0 + r0 + 16) * Kd + colu;
    const us* pb0 = Bt + (size_t)(n0 + r0) * Kd + colu;
    const us* pb1 = Bt + (size_t)(n0 + r0 + 16) * Kd + colu;
    auto lAs = (__attribute__((address_space(3))) us*)As;
    auto lBs = (__attribute__((address_space(3))) us*)Bs;
    int lbase = wave << 10;
    f32x4 acc[4][4] = {};
    for (int k0 = 0; k0 < Kd; k0 += 32) {
        __syncthreads();
        GLOAD16(pa0 + k0, lAs + lbase);
        GLOAD16(pa1 + k0, lAs + lbase + 512);
        GLOAD16(pb0 + k0, lBs + lbase);
        GLOAD16(pb1 + k0, lBs + lbase + 512);
        __syncthreads();
        bf16x8 afr[4], bfr[4];
#pragma unroll
        for (int i = 0; i < 4; i++) {
            afr[i] = *(const bf16x8*)&As[(wm + i * 16 + lm) * 32 + (quad << 3)];
            bfr[i] = *(const bf16x8*)&Bs[(wn + i * 16 + lm) * 32 + (quad << 3)];
        }
#pragma unroll
        for (int mf = 0; mf < 4; mf++)
#pragma unroll
            for (int nf = 0; nf < 4; nf++)
                acc[mf][nf] = __builtin_amdgcn_mfma_f32_16x16x32_bf16(afr[mf], bfr[nf], acc[mf][nf], 0, 0, 0);
    }
    float bvs[4];
#pragma unroll
    for (int nf = 0; nf < 4; nf++) bvs[nf] = bias[n0 + wn + nf * 16 + lm];
#pragma unroll
    for (int mf = 0; mf < 4; mf++) {
#pragma unroll
        for (int r = 0; r < 4; r++) {
            size_t row = (size_t)(m0 + wm + mf * 16 + (quad << 2) + r);
#pragma unroll
            for (int nf = 0; nf < 4; nf++) {
                float v = acc[mf][nf][r] + bvs[nf];
                if (EPI == 1) v = gelu_f(v);
                size_t ci = row * Nd + n0 + wn + nf * 16 + lm;
                if constexpr (OBF) ((us*)Cp)[ci] = f2b(v);
                else ((float*)Cp)[ci] = v;
            }
        }
    }
}

// ---------------- fused GEMM + LayerNorm: x' = LN(res + [acc+bias (*gamma*mask)]) ----------------
// tile 128(M) x 256(N=full D), 512 threads (8 waves, 2m x 4n).
template <bool PM, bool FINAL>
__global__ __launch_bounds__(512) void k_mgln(const us* __restrict__ A,
                                              const us* __restrict__ Bt,
                                              const float* __restrict__ bias,
                                              const float* __restrict__ res,
                                              const float* __restrict__ gamma,
                                              const float* __restrict__ mask,
                                              const float* __restrict__ lng,
                                              const float* __restrict__ lnb,
                                              const float* __restrict__ skip,
                                              float* __restrict__ xout,
                                              us* __restrict__ xbout,
                                              float* __restrict__ finout,
                                              int Kd) {
    __shared__ __align__(16) us As[128 * 32];
    __shared__ __align__(16) us Bs[256 * 32];
    __shared__ float2 part[4][128];
    __shared__ float2 stat[128];
    int tid = threadIdx.x;
    int m0 = blockIdx.x << 7;
    int wave = tid >> 6, lane = tid & 63;
    int wm = (wave & 1) << 6, wn = (wave >> 1) << 6;
    int grp = wave >> 1;
    int lm = lane & 15, quad = lane >> 4;
    // staging: A rows wave*16..+16 (1 load), B rows wave*32..+32 (2 loads)
    int ar = (wave << 4) + (lane >> 2);
    int br = (wave << 5) + (lane >> 2);
    int colu = (lane & 3) << 3;
    const us* pa = A + (size_t)(m0 + ar) * Kd + colu;
    const us* pb0 = Bt + (size_t)br * Kd + colu;
    const us* pb1 = Bt + (size_t)(br + 16) * Kd + colu;
    auto lAs = (__attribute__((address_space(3))) us*)As;
    auto lBs = (__attribute__((address_space(3))) us*)Bs;
    f32x4 acc[4][4] = {};
    for (int k0 = 0; k0 < Kd; k0 += 32) {
        __syncthreads();
        GLOAD16(pa + k0, lAs + (wave << 9));
        GLOAD16(pb0 + k0, lBs + (wave << 10));
        GLOAD16(pb1 + k0, lBs + (wave << 10) + 512);
        __syncthreads();
        bf16x8 afr[4], bfr[4];
#pragma unroll
        for (int i = 0; i < 4; i++) {
            afr[i] = *(const bf16x8*)&As[(wm + i * 16 + lm) * 32 + (quad << 3)];
            bfr[i] = *(const bf16x8*)&Bs[(wn + i * 16 + lm) * 32 + (quad << 3)];
        }
#pragma unroll
        for (int mf = 0; mf < 4; mf++)
#pragma unroll
            for (int nf = 0; nf < 4; nf++)
                acc[mf][nf] = __builtin_amdgcn_mfma_f32_16x16x32_bf16(afr[mf], bfr[nf], acc[mf][nf], 0, 0, 0);
    }
    // epilogue: v = res + (acc+bias)[*gamma*mask]; accumulate row stats
    float bvs[4], gms[4];
#pragma unroll
    for (int nf = 0; nf < 4; nf++) {
        int col = wn + nf * 16 + lm;
        bvs[nf] = bias[col];
        if (PM) gms[nf] = gamma[col];
    }
#pragma unroll
    for (int mf = 0; mf < 4; mf++) {
#pragma unroll
        for (int r = 0; r < 4; r++) {
            int rowl = wm + mf * 16 + (quad << 2) + r;
            size_t row = (size_t)(m0 + rowl);
            float mrow = PM ? mask[row] : 0.f;
            float s1 = 0.f, s2 = 0.f;
#pragma unroll
            for (int nf = 0; nf < 4; nf++) {
                int col = wn + nf * 16 + lm;
                float rv = res[row * 256 + col];
                float v = acc[mf][nf][r] + bvs[nf];
                v = PM ? fmaf(v * gms[nf], mrow, rv) : rv + v;
                acc[mf][nf][r] = v;
                s1 += v; s2 += v * v;
            }
            s1 += __shfl_xor(s1, 1, 64); s2 += __shfl_xor(s2, 1, 64);
            s1 += __shfl_xor(s1, 2, 64); s2 += __shfl_xor(s2, 2, 64);
            s1 += __shfl_xor(s1, 4, 64); s2 += __shfl_xor(s2, 4, 64);
            s1 += __shfl_xor(s1, 8, 64); s2 += __shfl_xor(s2, 8, 64);
            if (lm == 0) { float2 p; p.x = s1; p.y = s2; part[grp][rowl] = p; }
        }
    }
    __syncthreads();
    if (tid < 128) {
        float2 p0 = part[0][tid], p1 = part[1][tid], p2 = part[2][tid], p3 = part[3][tid];
        float s = p0.x + p1.x + p2.x + p3.x;
        float q = p0.y + p1.y + p2.y + p3.y;
        float mean = s * (1.f / 256.f);
        float var = q * (1.f / 256.f) - mean * mean;
        float2 st; st.x = mean; st.y = rsqrtf(var + 1e-5f);
        stat[tid] = st;
    }
    __syncthreads();
    float gvs[4], bts[4];
#pragma unroll
    for (int nf = 0; nf < 4; nf++) {
        int col = wn + nf * 16 + lm;
        gvs[nf] = lng[col];
        bts[nf] = lnb[col];
    }
#pragma unroll
    for (int mf = 0; mf < 4; mf++) {
#pragma unroll
        for (int r = 0; r < 4; r++) {
            int rowl = wm + mf * 16 + (quad << 2) + r;
            size_t row = (size_t)(m0 + rowl);
            float2 st = stat[rowl];
#pragma unroll
            for (int nf = 0; nf < 4; nf++) {
                int col = wn + nf * 16 + lm;
                float nv = fmaf((acc[mf][nf][r] - st.x) * st.y, gvs[nf], bts[nf]);
                xout[row * 256 + col] = nv;
                xbout[row * 256 + col] = f2b(nv);
                if (FINAL) finout[row * 256 + col] = nv + skip[row * 256 + col];
            }
        }
    }
}

// ---------------- fused KNN GEMM2, BK=64: h2 = gelu(gelu(P[nb]+Q[t]) @ w2t^T + b2) ----------------
__global__ __launch_bounds__(512) void k_knng(const us* __restrict__ pq,
                                              const int* __restrict__ idx,
                                              const us* __restrict__ Bt,
                                              const float* __restrict__ bias,
                                              us* __restrict__ h2b) {
    __shared__ __align__(16) us As[128 * 64];
    __shared__ __align__(16) us Bs[256 * 64];
    int tid = threadIdx.x;
    int m0 = blockIdx.x << 7;
    int wave = tid >> 6, lane = tid & 63;
    int wm = (wave & 1) << 6, wn = (wave >> 1) << 6;
    int lm = lane & 15, quad = lane >> 4;
    // A staging: thread -> row tid/4, 16 cols at (tid&3)*16
    int arow = tid >> 2, acolu = (tid & 3) << 4;
    int r = m0 + arow;
    int tok = r / 10;
    int nb = idx[r];
    int prow = (tok & ~127) + nb;
    const us* Pp = pq + (size_t)prow * 1024 + acolu;
    const us* Qp = pq + (size_t)tok * 1024 + 512 + acolu;
    // B staging: wave stages rows wave*32..+32, 4 GLOAD16 rounds of 8 rows
    int brow = (wave << 5) + (lane >> 3);
    int bcol = (lane & 7) << 3;
    const us* pb = Bt + (size_t)brow * 512 + bcol;
    auto lBs = (__attribute__((address_space(3))) us*)Bs;
    int lbase = wave << 11;
    f32x4 acc[4][4] = {};
    for (int k0 = 0; k0 < 512; k0 += 64) {
        uint4 pv0 = *(const uint4*)(Pp + k0);
        uint4 pv1 = *(const uint4*)(Pp + k0 + 8);
        uint4 qv0 = *(const uint4*)(Qp + k0);
        uint4 qv1 = *(const uint4*)(Qp + k0 + 8);
        uint4 h0, h1;
        h0.x = pk2(gelu_f(blo(pv0.x) + blo(qv0.x)), gelu_f(bhi(pv0.x) + bhi(qv0.x)));
        h0.y = pk2(gelu_f(blo(pv0.y) + blo(qv0.y)), gelu_f(bhi(pv0.y) + bhi(qv0.y)));
        h0.z = pk2(gelu_f(blo(pv0.z) + blo(qv0.z)), gelu_f(bhi(pv0.z) + bhi(qv0.z)));
        h0.w = pk2(gelu_f(blo(pv0.w) + blo(qv0.w)), gelu_f(bhi(pv0.w) + bhi(qv0.w)));
        h1.x = pk2(gelu_f(blo(pv1.x) + blo(qv1.x)), gelu_f(bhi(pv1.x) + bhi(qv1.x)));
        h1.y = pk2(gelu_f(blo(pv1.y) + blo(qv1.y)), gelu_f(bhi(pv1.y) + bhi(qv1.y)));
        h1.z = pk2(gelu_f(blo(pv1.z) + blo(qv1.z)), gelu_f(bhi(pv1.z) + bhi(qv1.z)));
        h1.w = pk2(gelu_f(blo(pv1.w) + blo(qv1.w)), gelu_f(bhi(pv1.w) + bhi(qv1.w)));
        __syncthreads();
        GLOAD16(pb + k0, lBs + lbase);
        GLOAD16(pb + k0 + 8 * 512, lBs + lbase + 512);
        GLOAD16(pb + k0 + 16 * 512, lBs + lbase + 1024);
        GLOAD16(pb + k0 + 24 * 512, lBs + lbase + 1536);
        *(uint4*)&As[arow * 64 + acolu] = h0;
        *(uint4*)&As[arow * 64 + acolu + 8] = h1;
        __syncthreads();
#pragma unroll
        for (int sub = 0; sub < 2; sub++) {
            bf16x8 afr[4], bfr[4];
#pragma unroll
            for (int i = 0; i < 4; i++) {
                afr[i] = *(const bf16x8*)&As[(wm + i * 16 + lm) * 64 + sub * 32 + (quad << 3)];
                bfr[i] = *(const bf16x8*)&Bs[(wn + i * 16 + lm) * 64 + sub * 32 + (quad << 3)];
            }
#pragma unroll
            for (int mf = 0; mf < 4; mf++)
#pragma unroll
                for (int nf = 0; nf < 4; nf++)
                    acc[mf][nf] = __builtin_amdgcn_mfma_f32_16x16x32_bf16(afr[mf], bfr[nf], acc[mf][nf], 0, 0, 0);
        }
    }
    float bvs[4];
#pragma unroll
    for (int nf = 0; nf < 4; nf++) bvs[nf] = bias[wn + nf * 16 + lm];
#pragma unroll
    for (int mf = 0; mf < 4; mf++) {
#pragma unroll
        for (int rr = 0; rr < 4; rr++) {
            size_t row = (size_t)(m0 + wm + mf * 16 + (quad << 2) + rr);
#pragma unroll
            for (int nf = 0; nf < 4; nf++) {
                float v = gelu_f(acc[mf][nf][rr] + bvs[nf]);
                h2b[row * 256 + wn + nf * 16 + lm] = f2b(v);
            }
        }
    }
}

// ---------------- pass-1 mean + shift + rownorm: lf1b, big(shifted), r ----------------
__global__ __launch_bounds__(64) void k_mean1s(const us* __restrict__ h2b,
                                               const float* __restrict__ mask,
                                               us* __restrict__ lfb,
                                               float* __restrict__ big,
                                               float* __restrict__ r) {
    int t = blockIdx.x, lane = threadIdx.x;
    int c = lane << 2;
    const us* p = h2b + (size_t)t * Kn * 256 + c;
    float s0 = 0.f, s1 = 0.f, s2 = 0.f, s3 = 0.f;
#pragma unroll
    for (int k = 0; k < Kn; k++) {
        uint2 v = *(const uint2*)(p + k * 256);
        s0 += blo(v.x); s1 += bhi(v.x);
        s2 += blo(v.y); s3 += bhi(v.y);
    }
    s0 *= 0.1f; s1 *= 0.1f; s2 *= 0.1f; s3 *= 0.1f;
    uint2 ob; ob.x = pk2(s0, s1); ob.y = pk2(s2, s3);
    *(uint2*)&lfb[(size_t)t * 256 + c] = ob;
    float sh = 999.f * (1.f - mask[t]);
    float4 w; w.x = s0 + sh; w.y = s1 + sh; w.z = s2 + sh; w.w = s3 + sh;
    *(float4*)&big[(size_t)t * 256 + c] = w;
    float sq = w.x * w.x + w.y * w.y + w.z * w.z + w.w * w.w;
#pragma unroll
    for (int off = 32; off; off >>= 1) sq += __shfl_xor(sq, off, 64);
    if (lane == 0) r[t] = sq;
}

// ---------------- pass-2 mean -> lf2 f32 ----------------
__global__ __launch_bounds__(256) void k_mean2(const us* __restrict__ h2b,
                                               float* __restrict__ lf) {
    int t = blockIdx.x, c = threadIdx.x;
    const us* p = h2b + (size_t)t * Kn * 256 + c;
    float s = 0.f;
#pragma unroll
    for (int k = 0; k < Kn; k++) s += blo((unsigned)p[k * 256]);
    lf[(size_t)t * 256 + c] = s * 0.1f;
}

// ---------------- time / fourier MLP ----------------
__global__ __launch_bounds__(256) void k_time(const float* __restrict__ tin,
                                              const float* __restrict__ w1,
                                              const float* __restrict__ w2,
                                              const float* __restrict__ tw,
                                              float* __restrict__ u) {
    __shared__ float e[256], e1[512], t2[256];
    int b = blockIdx.x, tid = threadIdx.x;
    float tv = tin[b];
    if (tid < 128) {
        const float emb = 0.07252236513366287f;
        float fr = expf(-emb * (float)tid);
        float ang = tv * fr * 1000.f;
        e[tid] = sinf(ang);
        e[tid + 128] = cosf(ang);
    }
    __syncthreads();
    for (int j = tid; j < 512; j += 256) {
        float s = 0.f;
        for (int i = 0; i < 256; i++) s += e[i] * w1[(size_t)i * 512 + j];
        e1[j] = s / (1.f + expf(-s));
    }
    __syncthreads();
    {
        float s = 0.f;
        for (int i = 0; i < 512; i++) s += e1[i] * w2[(size_t)i * 256 + tid];
        t2[tid] = s / (1.f + expf(-s));
    }
    __syncthreads();
    for (int j = tid; j < 512; j += 256) {
        float s = 0.f;
        for (int i = 0; i < 256; i++) s += t2[i] * tw[(size_t)i * 512 + j];
        u[(size_t)b * 512 + j] = s;
    }
}

// ---------------- knn top-k on 2-d points ----------------
__global__ __launch_bounds__(128) void k_topk2(const float* __restrict__ pts,
                                               const float* __restrict__ mask,
                                               int* __restrict__ idx) {
    int b = blockIdx.x, n = threadIdx.x;
    __shared__ float px[Nn], py[Nn], rr[Nn];
    float shift = 999.f * (1.f - mask[b * Nn + n]);
    float x = pts[(size_t)(b * Nn + n) * 2 + 0] + shift;
    float y = pts[(size_t)(b * Nn + n) * 2 + 1] + shift;
    px[n] = x; py[n] = y; rr[n] = x * x + y * y;
    __syncthreads();
    float rn = rr[n];
    float bd[Kn + 1]; int bi[Kn + 1];
#pragma unroll
    for (int j = 0; j <= Kn; j++) { bd[j] = 3.4e38f; bi[j] = -1; }
    for (int m = 0; m < Nn; m++) {
        float d = rn - 2.f * (x * px[m] + y * py[m]) + rr[m];
        if (d < bd[Kn]) {
            int j = Kn;
            while (j > 0 && d < bd[j - 1]) { bd[j] = bd[j - 1]; bi[j] = bi[j - 1]; j--; }
            bd[j] = d; bi[j] = m;
        }
    }
    for (int j = 1; j <= Kn; j++) idx[(size_t)(b * Nn + n) * Kn + j - 1] = bi[j];
}

__global__ __launch_bounds__(256) void k_dist(const float* __restrict__ fe,
                                              const float* __restrict__ r,
                                              float* __restrict__ Dm) {
    int b = blockIdx.z;
    int m0 = blockIdx.x * 64, n0 = blockIdx.y * 64;
    const float* A = fe + (size_t)b * Nn * Dn;
    __shared__ float As[16][68];
    __shared__ float Bs[16][68];
    int tid = threadIdx.x;
    int tx = tid & 15, ty = tid >> 4;
    int ar = tid >> 2, ac = (tid & 3) << 2;
    float acc[4][4] = {};
    for (int k0 = 0; k0 < Dn; k0 += 16) {
        float4 av = *(const float4*)&A[(size_t)(n0 + ar) * Dn + k0 + ac];
        float4 bv = *(const float4*)&A[(size_t)(m0 + ar) * Dn + k0 + ac];
        __syncthreads();
        As[ac + 0][ar] = av.x; As[ac + 1][ar] = av.y; As[ac + 2][ar] = av.z; As[ac + 3][ar] = av.w;
        Bs[ac + 0][ar] = bv.x; Bs[ac + 1][ar] = bv.y; Bs[ac + 2][ar] = bv.z; Bs[ac + 3][ar] = bv.w;
        __syncthreads();
#pragma unroll
        for (int kk = 0; kk < 16; kk++) {
            float4 a = *(const float4*)&As[kk][ty << 2];
            float4 b2 = *(const float4*)&Bs[kk][tx << 2];
            acc[0][0] += a.x * b2.x; acc[0][1] += a.x * b2.y; acc[0][2] += a.x * b2.z; acc[0][3] += a.x * b2.w;
            acc[1][0] += a.y * b2.x; acc[1][1] += a.y * b2.y; acc[1][2] += a.y * b2.z; acc[1][3] += a.y * b2.w;
            acc[2][0] += a.z * b2.x; acc[2][1] += a.z * b2.y; acc[2][2] += a.z * b2.z; acc[2][3] += a.z * b2.w;
            acc[3][0] += a.w * b2.x; acc[3][1] += a.w * b2.y; acc[3][2] += a.w * b2.z; acc[3][3] += a.w * b2.w;
        }
    }
    float4 rm = *(const float4*)&r[b * Nn + m0 + (tx << 2)];
#pragma unroll
    for (int i = 0; i < 4; i++) {
        int n = n0 + (ty << 2) + i;
        float rn = r[b * Nn + n];
        float4 v;
        v.x = rn - 2.f * acc[i][0] + rm.x;
        v.y = rn - 2.f * acc[i][1] + rm.y;
        v.z = rn - 2.f * acc[i][2] + rm.z;
        v.w = rn - 2.f * acc[i][3] + rm.w;
        *(float4*)&Dm[(size_t)b * Nn * Nn + (size_t)n * Nn + m0 + (tx << 2)] = v;
    }
}

__global__ __launch_bounds__(128) void k_topkg(const float* __restrict__ Dm, int* __restrict__ idx) {
    int b = blockIdx.x, n = threadIdx.x;
    const float* row = Dm + (size_t)b * Nn * Nn + (size_t)n * Nn;
    float bd[Kn + 1]; int bi[Kn + 1];
#pragma unroll
    for (int j = 0; j <= Kn; j++) { bd[j] = 3.4e38f; bi[j] = -1; }
    for (int m = 0; m < Nn; m++) {
        float d = row[m];
        if (d < bd[Kn]) {
            int j = Kn;
            while (j > 0 && d < bd[j - 1]) { bd[j] = bd[j - 1]; bi[j] = bi[j - 1]; j--; }
            bd[j] = d; bi[j] = m;
        }
    }
    for (int j = 1; j <= Kn; j++) idx[(size_t)(b * Nn + n) * Kn + j - 1] = bi[j];
}

// ---------------- combine ----------------
__global__ void k_combine(const float* __restrict__ u, const float* __restrict__ mask,
                          const float* __restrict__ lf2, float* __restrict__ x,
                          float* __restrict__ skip, us* __restrict__ xb) {
    int gid = blockIdx.x * 256 + threadIdx.x;
    int t = gid >> 6;
    int c = (gid & 63) << 2;
    int b = t >> 7;
    float m = mask[t];
    float4 xv = *(const float4*)&x[(size_t)t * Dn + c];
    float4 lv = *(const float4*)&lf2[(size_t)t * Dn + c];
    float4 sc = *(const float4*)&u[(size_t)b * 512 + c];
    float4 sh = *(const float4*)&u[(size_t)b * 512 + 256 + c];
    float4 v;
    v.x = xv.x * (1.f + m * sc.x) + m * sh.x + lv.x;
    v.y = xv.y * (1.f + m * sc.y) + m * sh.y + lv.y;
    v.z = xv.z * (1.f + m * sc.z) + m * sh.z + lv.z;
    v.w = xv.w * (1.f + m * sc.w) + m * sh.w + lv.w;
    *(float4*)&x[(size_t)t * Dn + c] = v;
    *(float4*)&skip[(size_t)t * Dn + c] = v;
    uint2 p; p.x = pk2(v.x, v.y); p.y = pk2(v.z, v.w);
    *(uint2*)&xb[(size_t)t * Dn + c] = p;
}

// ---------------- MFMA attention ----------------
__global__ __launch_bounds__(256) void k_attn(const us* __restrict__ qkv,
                                              const float* __restrict__ mask,
                                              us* __restrict__ outp) {
    __shared__ __align__(16) us Qs[128 * 40];
    __shared__ __align__(16) us Ks[128 * 40];
    __shared__ __align__(16) us Vt[32 * 136];
    __shared__ __align__(16) us Ps[128 * 136];
    __shared__ float msk[128];
    int bh = blockIdx.x;
    int b = bh >> 3, h = bh & 7;
    int tid = threadIdx.x;
    int wave = tid >> 6, lane = tid & 63;
    int lm = lane & 15, quad = lane >> 4;
    int wm = wave << 5;
    {
        int row = tid >> 1, off = (tid & 1) << 4;
        const us* rp = qkv + (size_t)(b * 128 + row) * 768 + h * 32 + off;
        *(uint4*)&Qs[row * 40 + off] = *(const uint4*)(rp);
        *(uint4*)&Qs[row * 40 + off + 8] = *(const uint4*)(rp + 8);
        *(uint4*)&Ks[row * 40 + off] = *(const uint4*)(rp + 256);
        *(uint4*)&Ks[row * 40 + off + 8] = *(const uint4*)(rp + 264);
        union { uint4 u[2]; us s[16]; } tv;
        tv.u[0] = *(const uint4*)(rp + 512);
        tv.u[1] = *(const uint4*)(rp + 520);
#pragma unroll
        for (int j = 0; j < 16; j++) Vt[(off + j) * 136 + row] = tv.s[j];
        if (tid < 128) msk[tid] = mask[b * 128 + tid];
    }
    __syncthreads();
    f32x4 acc[2][8] = {};
    {
        bf16x8 aq[2];
#pragma unroll
        for (int mf = 0; mf < 2; mf++)
            aq[mf] = *(const bf16x8*)&Qs[(wm + mf * 16 + lm) * 40 + (quad << 3)];
#pragma unroll
        for (int nf = 0; nf < 8; nf++) {
            bf16x8 bk = *(const bf16x8*)&Ks[(nf * 16 + lm) * 40 + (quad << 3)];
            acc[0][nf] = __builtin_amdgcn_mfma_f32_16x16x32_bf16(aq[0], bk, acc[0][nf], 0, 0, 0);
            acc[1][nf] = __builtin_amdgcn_mfma_f32_16x16x32_bf16(aq[1], bk, acc[1][nf], 0, 0, 0);
        }
    }
    {
        const float sc = 0.17677669529663687f;
        float mkc[8];
#pragma unroll
        for (int nf = 0; nf < 8; nf++) mkc[nf] = msk[nf * 16 + lm];
#pragma unroll
        for (int mf = 0; mf < 2; mf++) {
#pragma unroll
            for (int nf = 0; nf < 8; nf++)
#pragma unroll
                for (int r = 0; r < 4; r++) {
                    float s = acc[mf][nf][r];
                    acc[mf][nf][r] = mkc[nf] > 0.f ? s * sc : -1.0e9f;
                }
#pragma unroll
            for (int r = 0; r < 4; r++) {
                float m = acc[mf][0][r];
#pragma unroll
                for (int nf = 1; nf < 8; nf++) m = fmaxf(m, acc[mf][nf][r]);
                m = fmaxf(m, __shfl_xor(m, 1, 64));
                m = fmaxf(m, __shfl_xor(m, 2, 64));
                m = fmaxf(m, __shfl_xor(m, 4, 64));
                m = fmaxf(m, __shfl_xor(m, 8, 64));
                float s = 0.f;
#pragma unroll
                for (int nf = 0; nf < 8; nf++) {
                    float p = __expf(acc[mf][nf][r] - m);
                    acc[mf][nf][r] = p;
                    s += p;
                }
                s += __shfl_xor(s, 1, 64);
                s += __shfl_xor(s, 2, 64);
                s += __shfl_xor(s, 4, 64);
                s += __shfl_xor(s, 8, 64);
                float linv = __builtin_amdgcn_rcpf(s);
                int prow = wm + mf * 16 + (quad << 2) + r;
#pragma unroll
                for (int nf = 0; nf < 8; nf++)
                    Ps[prow * 136 + nf * 16 + lm] = f2b(acc[mf][nf][r] * linv);
            }
        }
    }
    __syncthreads();
    f32x4 oacc[2][2] = {};
    for (int kt = 0; kt < 4; kt++) {
        bf16x8 ap[2], bv[2];
#pragma unroll
        for (int mf = 0; mf < 2; mf++)
            ap[mf] = *(const bf16x8*)&Ps[(wm + mf * 16 + lm) * 136 + kt * 32 + (quad << 3)];
#pragma unroll
        for (int nf = 0; nf < 2; nf++)
            bv[nf] = *(const bf16x8*)&Vt[(nf * 16 + lm) * 136 + kt * 32 + (quad << 3)];
#pragma unroll
        for (int mf = 0; mf < 2; mf++)
#pragma unroll
            for (int nf = 0; nf < 2; nf++)
                oacc[mf][nf] = __builtin_amdgcn_mfma_f32_16x16x32_bf16(ap[mf], bv[nf], oacc[mf][nf], 0, 0, 0);
    }
#pragma unroll
    for (int mf = 0; mf < 2; mf++)
#pragma unroll
        for (int r = 0; r < 4; r++) {
            int row = wm + mf * 16 + (quad << 2) + r;
#pragma unroll
            for (int nf = 0; nf < 2; nf++)
                outp[(size_t)(b * 128 + row) * 256 + h * 32 + nf * 16 + lm] = f2b(oacc[mf][nf][r]);
        }
}

extern "C" void kernel_launch(void* const* d_in, const int* in_sizes, int n_in,
                              void* d_out, int out_size, void* d_ws, size_t ws_size,
                              hipStream_t stream) {
    (void)in_sizes; (void)n_in; (void)out_size; (void)d_ws; (void)ws_size;
    const float* f_feat = (const float*)d_in[0];
    const float* f_pts  = (const float*)d_in[1];
    const float* f_mask = (const float*)d_in[2];
    const float* f_time = (const float*)d_in[3];
    const float* enc_w1 = (const float*)d_in[4];
    const float* enc_b1 = (const float*)d_in[5];
    const float* enc_w2 = (const float*)d_in[6];
    const float* enc_b2 = (const float*)d_in[7];
    const float* four_w1 = (const float*)d_in[8];
    const float* four_w2 = (const float*)d_in[9];
    const float* time_w = (const float*)d_in[10];
    const float* l1w1 = (const float*)d_in[11];
    const float* l1b1 = (const float*)d_in[12];
    const float* l1w2 = (const float*)d_in[13];
    const float* l1b2 = (const float*)d_in[14];
    const float* l2w1 = (const float*)d_in[15];
    const float* l2b1 = (const float*)d_in[16];
    const float* l2w2 = (const float*)d_in[17];
    const float* l2b2 = (const float*)d_in[18];
    const float* qkv_w = (const float*)d_in[19];
    const float* qkv_b = (const float*)d_in[20];
    const float* out_w = (const float*)d_in[21];
    const float* out_b = (const float*)d_in[22];
    const float* ln1g = (const float*)d_in[23];
    const float* ln1b = (const float*)d_in[24];
    const float* ff1w = (const float*)d_in[25];
    const float* ff1b = (const float*)d_in[26];
    const float* ff2w = (const float*)d_in[27];
    const float* ff2b = (const float*)d_in[28];
    const float* gam  = (const float*)d_in[29];
    const float* ln2g = (const float*)d_in[30];
    const float* ln2b = (const float*)d_in[31];
    float* out = (float*)d_out;

    float *x, *skip, *lf2, *dm, *big, *u, *r, *pqbias;
    int* idx;
    us *bigb, *xb, *attb, *lf1b, *pq, *h2b, *feat16, *wt;
    hipGetSymbolAddress((void**)&x,    HIP_SYMBOL(g_x));
    hipGetSymbolAddress((void**)&skip, HIP_SYMBOL(g_skip));
    hipGetSymbolAddress((void**)&lf2,  HIP_SYMBOL(g_lf2));
    hipGetSymbolAddress((void**)&dm,   HIP_SYMBOL(g_dm));
    hipGetSymbolAddress((void**)&big,  HIP_SYMBOL(g_big));
    hipGetSymbolAddress((void**)&u,    HIP_SYMBOL(g_u));
    hipGetSymbolAddress((void**)&r,    HIP_SYMBOL(g_r));
    hipGetSymbolAddress((void**)&pqbias, HIP_SYMBOL(g_pqbias));
    hipGetSymbolAddress((void**)&idx,  HIP_SYMBOL(g_idx));
    hipGetSymbolAddress((void**)&bigb, HIP_SYMBOL(g_bigb));
    hipGetSymbolAddress((void**)&xb,   HIP_SYMBOL(g_xb));
    hipGetSymbolAddress((void**)&attb, HIP_SYMBOL(g_attb));
    hipGetSymbolAddress((void**)&lf1b, HIP_SYMBOL(g_lf1b));
    hipGetSymbolAddress((void**)&pq,   HIP_SYMBOL(g_pq));
    hipGetSymbolAddress((void**)&h2b,  HIP_SYMBOL(g_h2b));
    hipGetSymbolAddress((void**)&feat16, HIP_SYMBOL(g_feat16));
    hipGetSymbolAddress((void**)&wt,   HIP_SYMBOL(g_wt));

    // ---- weight prep ----
    k_prep<<<dim3(16, 1, 1), 256, 0, stream>>>(enc_w1, wt + OFF_ENC1, 13, 32, 512, 0, 0);
    k_prep<<<dim3(8, 16, 1), 256, 0, stream>>>(enc_w2, wt + OFF_ENC2, 512, 512, 256, 0, 0);
    k_prep<<<dim3(8, 16, 1), 256, 0, stream>>>(l1w2, wt + OFF_W2A, 512, 512, 256, 0, 0);
    k_prep<<<dim3(8, 16, 1), 256, 0, stream>>>(l2w2, wt + OFF_W2B, 512, 512, 256, 0, 0);
    k_prepPQ<<<1024, 64, 0, stream>>>(l1w1, l1b1, wt + OFF_PQ1, pqbias, 13, 32);
    k_prepPQ<<<1024, 256, 0, stream>>>(l2w1, l2b1, wt + OFF_PQ2, pqbias + 1024, 256, 256);
    k_prep<<<dim3(24, 8, 8), 256, 0, stream>>>(qkv_w, wt + OFF_QKV, 256, 256, 768, 256 * 768, 768 * 256);
    k_prep<<<dim3(8, 8, 8), 256, 0, stream>>>(out_w, wt + OFF_OUT, 256, 256, 256, 256 * 256, 256 * 256);
    k_prep<<<dim3(16, 8, 8), 256, 0, stream>>>(ff1w, wt + OFF_FF1, 256, 256, 512, 256 * 512, 512 * 256);
    k_prep<<<dim3(8, 16, 8), 256, 0, stream>>>(ff2w, wt + OFF_FF2, 512, 512, 256, 512 * 256, 256 * 512);
    k_featpad<<<Tn * 32 / 256, 256, 0, stream>>>(f_feat, feat16);

    // ---- time embedding ----
    k_time<<<Bn, 256, 0, stream>>>(f_time, four_w1, four_w2, time_w, u);
    // ---- encoder (both stages MFMA) ----
    k_mg2<1, true><<<dim3(4, 128), 256, 0, stream>>>(feat16, wt + OFF_ENC1, enc_b1, bigb, 32, 512);
    k_mg2<1, false><<<dim3(2, 128), 256, 0, stream>>>(bigb, wt + OFF_ENC2, enc_b2, x, 512, 256);
    // ---- knn pass 1 ----
    k_topk2<<<Bn, Nn, 0, stream>>>(f_pts, f_mask, idx);
    k_mg2<0, true><<<dim3(8, 128), 256, 0, stream>>>(feat16, wt + OFF_PQ1, pqbias, pq, 32, 1024);
    k_knng<<<Rn / 128, 512, 0, stream>>>(pq, idx, wt + OFF_W2A, l1b2, h2b);
    k_mean1s<<<Tn, 64, 0, stream>>>(h2b, f_mask, lf1b, big, r);
    // ---- knn pass 2 ----
    k_dist<<<dim3(2, 2, Bn), 256, 0, stream>>>(big, r, dm);
    k_topkg<<<Bn, Nn, 0, stream>>>(dm, idx);
    k_mg2<0, true><<<dim3(8, 128), 256, 0, stream>>>(lf1b, wt + OFF_PQ2, pqbias + 1024, pq, 256, 1024);
    k_knng<<<Rn / 128, 512, 0, stream>>>(pq, idx, wt + OFF_W2B, l2b2, h2b);
    k_mean2<<<Tn, 256, 0, stream>>>(h2b, lf2);
    // ---- combine ----
    k_combine<<<Tn * 64 / 256, 256, 0, stream>>>(u, f_mask, lf2, x, skip, xb);
    // ---- transformer layers ----
    for (int l = 0; l < Ln; l++) {
        k_mg2<0, true><<<dim3(6, 128), 256, 0, stream>>>(
            xb, wt + OFF_QKV + (size_t)l * 768 * 256, qkv_b + l * 768, bigb, 256, 768);
        k_attn<<<Bn * 8, 256, 0, stream>>>(bigb, f_mask, attb);
        k_mgln<false, false><<<128, 512, 0, stream>>>(
            attb, wt + OFF_OUT + (size_t)l * 256 * 256, out_b + l * 256,
            x, nullptr, f_mask, ln1g + l * Dn, ln1b + l * Dn, nullptr, x, xb, nullptr, 256);
        k_mg2<1, true><<<dim3(4, 128), 256, 0, stream>>>(
            xb, wt + OFF_FF1 + (size_t)l * 512 * 256, ff1b + l * 512, bigb, 256, 512);
        if (l < Ln - 1)
            k_mgln<true, false><<<128, 512, 0, stream>>>(
                bigb, wt + OFF_FF2 + (size_t)l * 256 * 512, ff2b + l * 256,
                x, gam + l * Dn, f_mask, ln2g + l * Dn, ln2b + l * Dn, nullptr, x, xb, nullptr, 512);
        else
            k_mgln<true, true><<<128, 512, 0, stream>>>(
                bigb, wt + OFF_FF2 + (size_t)l * 256 * 512, ff2b + l * 256,
                x, gam + l * Dn, f_mask, ln2g + l * Dn, ln2b + l * Dn, skip, x, xb, out, 512);
    }
}